// Round 2
// baseline (544.594 us; speedup 1.0000x reference)
//
#include <hip/hip_runtime.h>
#include <hip/hip_bf16.h>
#include <stdint.h>

// ---------------------------------------------------------------------------
// TransformerDecoderBlock on MI355X (gfx950).  B=2, T=2048, C=1024, H=16, hd=64.
// R1: m97-style GEMM (global_load_lds w=16 + XOR-swizzled LDS), barrier-free
//     register flash attention with pre-transposed V.
// ---------------------------------------------------------------------------

typedef __attribute__((ext_vector_type(8))) short bf16x8;   // 8 bf16 in 4 VGPRs
typedef __attribute__((ext_vector_type(4))) float f32x4;

#define MFMA16(a, b, c) __builtin_amdgcn_mfma_f32_16x16x32_bf16((a), (b), (c), 0, 0, 0)

__device__ __forceinline__ void gload16(const void* g, void* l) {
    __builtin_amdgcn_global_load_lds(
        (const __attribute__((address_space(1))) char*)g,
        (__attribute__((address_space(3))) char*)l, 16, 0, 0);
}

// --------------------------- transpose + fp32->bf16 ------------------------
// in: fp32 [K, N] row-major  ->  out: bf16 [N, K] row-major
__global__ __launch_bounds__(256) void tconv_k(const float* __restrict__ in,
                                               __hip_bfloat16* __restrict__ out,
                                               int K, int N) {
    __shared__ float tile[32][33];
    const int n0 = blockIdx.x * 32, k0 = blockIdx.y * 32;
    const int tx = threadIdx.x, ty = threadIdx.y;   // block (32, 8)
    for (int i = ty; i < 32; i += 8)
        tile[i][tx] = in[(size_t)(k0 + i) * N + n0 + tx];
    __syncthreads();
    for (int i = ty; i < 32; i += 8)
        out[(size_t)(n0 + i) * K + k0 + tx] = __float2bfloat16(tile[tx][i]);
}

// --------------------------------- layernorm -------------------------------
__global__ __launch_bounds__(256) void ln_k(const float* __restrict__ x,
                                            const float* __restrict__ g,
                                            const float* __restrict__ beta,
                                            __hip_bfloat16* __restrict__ out) {
    const int row = blockIdx.x;
    const int tid = threadIdx.x;
    float4 v = ((const float4*)(x + (size_t)row * 1024))[tid];
    float s  = v.x + v.y + v.z + v.w;
    float s2 = v.x * v.x + v.y * v.y + v.z * v.z + v.w * v.w;
    for (int off = 1; off < 64; off <<= 1) {
        s  += __shfl_xor(s,  off, 64);
        s2 += __shfl_xor(s2, off, 64);
    }
    __shared__ float ss[4], ss2[4];
    const int w = tid >> 6, lane = tid & 63;
    if (lane == 0) { ss[w] = s; ss2[w] = s2; }
    __syncthreads();
    s  = ss[0] + ss[1] + ss[2] + ss[3];
    s2 = ss2[0] + ss2[1] + ss2[2] + ss2[3];
    const float mu  = s * (1.0f / 1024.0f);
    const float var = s2 * (1.0f / 1024.0f) - mu * mu;
    const float rs  = rsqrtf(var + 1e-5f);
    float4 gv = ((const float4*)g)[tid];
    float4 bv = ((const float4*)beta)[tid];
    __hip_bfloat16* o = out + (size_t)row * 1024 + tid * 4;
    o[0] = __float2bfloat16((v.x - mu) * rs * gv.x + bv.x);
    o[1] = __float2bfloat16((v.y - mu) * rs * gv.y + bv.y);
    o[2] = __float2bfloat16((v.z - mu) * rs * gv.z + bv.z);
    o[3] = __float2bfloat16((v.w - mu) * rs * gv.w + bv.w);
}

// ----------------------------------- GEMM ----------------------------------
// C[M,N] = A[M,K] @ Bt[N,K]^T (bf16), m97 structure: global_load_lds w=16.
// LDS tile [128][32] bf16 stored as 512 x 16B chunks; chunk (row r, kchunk c)
// lives at slot r*4 + ((c + (r>>1)) & 3)  -> conflict-free b128 readback.
template <int BIAS, int RELU, int RESID, int OUTBF>
__global__ __launch_bounds__(256, 3) void gemm_k(const __hip_bfloat16* __restrict__ A,
                                                 const __hip_bfloat16* __restrict__ Bt,
                                                 const float* __restrict__ bias,
                                                 const float* __restrict__ resid,
                                                 void* __restrict__ out,
                                                 int M, int N, int K) {
    __align__(16) __shared__ __hip_bfloat16 As[128 * 32];
    __align__(16) __shared__ __hip_bfloat16 Bs[128 * 32];

    const int tid  = threadIdx.x;
    const int lane = tid & 63, w = tid >> 6;
    const int wm = w >> 1, wn = w & 1;
    const int m0 = blockIdx.y * 128, n0 = blockIdx.x * 128;
    const int l16 = lane & 15, quad = lane >> 4;

    // staging: wave w, load0 -> rows w*16..+15, load1 -> rows 64+w*16..+15
    const int r0 = w * 16 + (lane >> 2);
    const int c0 = ((lane & 3) - ((r0 >> 1) & 3)) & 3;
    const int r1 = 64 + r0;
    const int c1 = ((lane & 3) - ((r1 >> 1) & 3)) & 3;
    const __hip_bfloat16* ga0 = A  + (size_t)(m0 + r0) * K + c0 * 8;
    const __hip_bfloat16* ga1 = A  + (size_t)(m0 + r1) * K + c1 * 8;
    const __hip_bfloat16* gb0 = Bt + (size_t)(n0 + r0) * K + c0 * 8;
    const __hip_bfloat16* gb1 = Bt + (size_t)(n0 + r1) * K + c1 * 8;

    // fragment LDS byte offsets (constant across K-loop)
    int offA[4], offB[4];
#pragma unroll
    for (int t = 0; t < 4; t++) {
        const int rA = wm * 64 + t * 16 + l16;
        offA[t] = (rA * 4 + ((quad + ((rA >> 1) & 3)) & 3)) * 16;
        const int rB = wn * 64 + t * 16 + l16;
        offB[t] = (rB * 4 + ((quad + ((rB >> 1) & 3)) & 3)) * 16;
    }

    f32x4 acc[4][4] = {};

    for (int k0 = 0; k0 < K; k0 += 32) {
        __syncthreads();   // prev iter's LDS reads complete
        gload16(ga0, As + w * 512);
        gload16(ga1, As + 2048 + w * 512);
        gload16(gb0, Bs + w * 512);
        gload16(gb1, Bs + 2048 + w * 512);
        ga0 += 32; ga1 += 32; gb0 += 32; gb1 += 32;
        __syncthreads();   // vmcnt drained -> tiles ready

        bf16x8 af[4], bfr[4];
#pragma unroll
        for (int t = 0; t < 4; t++) {
            af[t]  = *(const bf16x8*)((const char*)As + offA[t]);
            bfr[t] = *(const bf16x8*)((const char*)Bs + offB[t]);
        }
#pragma unroll
        for (int mt = 0; mt < 4; mt++)
#pragma unroll
            for (int nt = 0; nt < 4; nt++)
                acc[mt][nt] = MFMA16(af[mt], bfr[nt], acc[mt][nt]);
    }

    // epilogue: C/D layout col = lane&15, row = quad*4 + reg
#pragma unroll
    for (int mt = 0; mt < 4; mt++)
#pragma unroll
        for (int nt = 0; nt < 4; nt++) {
            const int row = m0 + wm * 64 + mt * 16 + quad * 4;
            const int col = n0 + wn * 64 + nt * 16 + l16;
            const float bv = BIAS ? bias[col] : 0.0f;
#pragma unroll
            for (int r = 0; r < 4; r++) {
                float v = acc[mt][nt][r] + bv;
                if (RELU) v = v > 0.0f ? v : 0.0f;
                const size_t idx = (size_t)(row + r) * N + col;
                if (RESID) v += resid[idx];
                if (OUTBF) ((__hip_bfloat16*)out)[idx] = __float2bfloat16(v);
                else       ((float*)out)[idx] = v;
            }
        }
}

// ----------------------- V transpose: qkv -> Vt[bh][d][T] -------------------
__global__ __launch_bounds__(256) void vtrans_k(const __hip_bfloat16* __restrict__ qkv,
                                                __hip_bfloat16* __restrict__ vt) {
    const int T = 2048, C3 = 3072;
    const int bh = blockIdx.y, b = bh >> 4, h = bh & 15;
    const int t0 = blockIdx.x * 64;
    const int tx = threadIdx.x, ty = threadIdx.y;   // block (64, 4)
    __shared__ __hip_bfloat16 tile[64][65];
#pragma unroll
    for (int j = 0; j < 16; j++) {
        const int tl = ty * 16 + j;
        tile[tl][tx] = qkv[(size_t)(b * T + t0 + tl) * C3 + 2048 + h * 64 + tx];
    }
    __syncthreads();
#pragma unroll
    for (int j = 0; j < 16; j++) {
        const int d = ty * 16 + j;
        vt[((size_t)bh * 64 + d) * 2048 + t0 + tx] = tile[tx][d];
    }
}

// ------------------------------ flash attention -----------------------------
// Barrier-free: K and V^T fragments read directly from global as b128 per lane.
// Block = (head, 64 q rows), 4 waves x 16 q rows.  Heavy qt dispatched first.
__global__ __launch_bounds__(256, 3) void attn_k(const __hip_bfloat16* __restrict__ qkv,
                                                 const __hip_bfloat16* __restrict__ vt,
                                                 __hip_bfloat16* __restrict__ outp) {
    const int T = 2048, C3 = 3072;
    const int bh = blockIdx.y, b = bh >> 4, h = bh & 15;
    const int qt = 31 - blockIdx.x;           // heavy blocks first
    const int q0 = qt * 64;
    const int tid = threadIdx.x, lane = tid & 63, w = tid >> 6;
    const int l16 = lane & 15, quad = lane >> 4;

    __align__(16) __shared__ __hip_bfloat16 Pw[4][16 * 72];

    const __hip_bfloat16* qptr = qkv + (size_t)(b * T + q0 + w * 16 + l16) * C3 + h * 64;
    bf16x8 qf0 = *(const bf16x8*)(qptr + quad * 8);
    bf16x8 qf1 = *(const bf16x8*)(qptr + 32 + quad * 8);
    const __hip_bfloat16* kbase = qkv + (size_t)(b * T) * C3 + 1024 + h * 64;
    const __hip_bfloat16* vbase = vt + (size_t)bh * 64 * 2048;

    f32x4 oacc[4] = {};
    float mrow[4], lrow[4];
#pragma unroll
    for (int r = 0; r < 4; r++) { mrow[r] = -3e38f; lrow[r] = 0.0f; }
    const float sc = 0.125f * 1.44269504f;   // exp2 domain

    for (int kt = 0; kt <= qt; kt++) {
        // ---- S = Q K^T (K B-frags direct from global) ----
        f32x4 s[4];
#pragma unroll
        for (int nt = 0; nt < 4; nt++) {
            const __hip_bfloat16* kr = kbase + (size_t)(kt * 64 + nt * 16 + l16) * C3;
            bf16x8 kf0 = *(const bf16x8*)(kr + quad * 8);
            bf16x8 kf1 = *(const bf16x8*)(kr + 32 + quad * 8);
            f32x4 z = {};
            z = MFMA16(qf0, kf0, z);
            z = MFMA16(qf1, kf1, z);
            s[nt] = z;
        }

        float mt4[4] = {-3e38f, -3e38f, -3e38f, -3e38f};
        if (kt == qt) {   // diagonal tile: causal mask
#pragma unroll
            for (int nt = 0; nt < 4; nt++) {
                const int col = nt * 16 + l16;
#pragma unroll
                for (int r = 0; r < 4; r++) {
                    const int row = w * 16 + quad * 4 + r;
                    float v = s[nt][r] * sc;
                    if (col > row) v = -3e38f;
                    s[nt][r] = v;
                    mt4[r] = fmaxf(mt4[r], v);
                }
            }
        } else {
#pragma unroll
            for (int nt = 0; nt < 4; nt++)
#pragma unroll
                for (int r = 0; r < 4; r++) {
                    const float v = s[nt][r] * sc;
                    s[nt][r] = v;
                    mt4[r] = fmaxf(mt4[r], v);
                }
        }
#pragma unroll
        for (int off = 1; off < 16; off <<= 1)
#pragma unroll
            for (int r = 0; r < 4; r++)
                mt4[r] = fmaxf(mt4[r], __shfl_xor(mt4[r], off, 64));

        float alpha[4], ls[4];
#pragma unroll
        for (int r = 0; r < 4; r++) {
            const float mnew = fmaxf(mrow[r], mt4[r]);
            alpha[r] = exp2f(mrow[r] - mnew);
            mrow[r] = mnew;
            ls[r] = 0.0f;
        }
#pragma unroll
        for (int nt = 0; nt < 4; nt++)
#pragma unroll
            for (int r = 0; r < 4; r++) {
                const float p = exp2f(s[nt][r] - mrow[r]);
                ls[r] += p;
                Pw[w][(quad * 4 + r) * 72 + nt * 16 + l16] = __float2bfloat16(p);
            }
#pragma unroll
        for (int off = 1; off < 16; off <<= 1)
#pragma unroll
            for (int r = 0; r < 4; r++)
                ls[r] += __shfl_xor(ls[r], off, 64);
#pragma unroll
        for (int r = 0; r < 4; r++) lrow[r] = lrow[r] * alpha[r] + ls[r];
#pragma unroll
        for (int dt = 0; dt < 4; dt++)
#pragma unroll
            for (int r = 0; r < 4; r++)
                oacc[dt][r] *= alpha[r];

        asm volatile("s_waitcnt lgkmcnt(0)" ::: "memory");  // own-wave P visible

        bf16x8 pf0 = *(const bf16x8*)(&Pw[w][l16 * 72 + quad * 8]);
        bf16x8 pf1 = *(const bf16x8*)(&Pw[w][l16 * 72 + 32 + quad * 8]);
#pragma unroll
        for (int dt = 0; dt < 4; dt++) {
            const __hip_bfloat16* vr = vbase + (size_t)(dt * 16 + l16) * 2048 + kt * 64;
            bf16x8 vf0 = *(const bf16x8*)(vr + quad * 8);
            bf16x8 vf1 = *(const bf16x8*)(vr + 32 + quad * 8);
            oacc[dt] = MFMA16(pf0, vf0, oacc[dt]);
            oacc[dt] = MFMA16(pf1, vf1, oacc[dt]);
        }
    }

    float rl[4];
#pragma unroll
    for (int r = 0; r < 4; r++) rl[r] = 1.0f / lrow[r];
#pragma unroll
    for (int dt = 0; dt < 4; dt++)
#pragma unroll
        for (int r = 0; r < 4; r++) {
            const int row = q0 + w * 16 + quad * 4 + r;
            outp[(size_t)(b * T + row) * 1024 + h * 64 + dt * 16 + l16] =
                __float2bfloat16(oacc[dt][r] * rl[r]);
        }
}

// --------------------------------- launcher --------------------------------
extern "C" void kernel_launch(void* const* d_in, const int* in_sizes, int n_in,
                              void* d_out, int out_size, void* d_ws, size_t ws_size,
                              hipStream_t stream) {
    const float* x     = (const float*)d_in[0];
    const float* Wqkv  = (const float*)d_in[1];
    const float* Wo    = (const float*)d_in[2];
    const float* b_o   = (const float*)d_in[3];
    const float* g1    = (const float*)d_in[4];
    const float* beta1 = (const float*)d_in[5];
    const float* g2    = (const float*)d_in[6];
    const float* beta2 = (const float*)d_in[7];
    const float* Wff1  = (const float*)d_in[8];
    const float* bff1  = (const float*)d_in[9];
    const float* Wff2  = (const float*)d_in[10];
    const float* bff2  = (const float*)d_in[11];

    char* ws = (char*)d_ws;
    size_t off = 0;
    auto alloc = [&](size_t bytes) {
        void* p = ws + off;
        off += (bytes + 255) & ~(size_t)255;
        return p;
    };
    __hip_bfloat16* Wqkv_t = (__hip_bfloat16*)alloc(3072ULL * 1024 * 2);
    __hip_bfloat16* Wo_t   = (__hip_bfloat16*)alloc(1024ULL * 1024 * 2);
    __hip_bfloat16* Wff1_t = (__hip_bfloat16*)alloc(4096ULL * 1024 * 2);
    __hip_bfloat16* Wff2_t = (__hip_bfloat16*)alloc(1024ULL * 4096 * 2);
    __hip_bfloat16* h_bf   = (__hip_bfloat16*)alloc(4096ULL * 1024 * 2);
    __hip_bfloat16* qkv_bf = (__hip_bfloat16*)alloc(4096ULL * 3072 * 2);
    __hip_bfloat16* att_bf = (__hip_bfloat16*)alloc(4096ULL * 1024 * 2);
    float*          x2     = (float*)alloc(4096ULL * 1024 * 4);
    __hip_bfloat16* ff1_bf = qkv_bf;              // dead by FF time
    __hip_bfloat16* vt     = (__hip_bfloat16*)x2; // dead before Wo-gemm writes x2

    const dim3 tb(32, 8);
    tconv_k<<<dim3(3072 / 32, 1024 / 32), tb, 0, stream>>>(Wqkv, Wqkv_t, 1024, 3072);
    tconv_k<<<dim3(1024 / 32, 1024 / 32), tb, 0, stream>>>(Wo,   Wo_t,   1024, 1024);
    tconv_k<<<dim3(4096 / 32, 1024 / 32), tb, 0, stream>>>(Wff1, Wff1_t, 1024, 4096);
    tconv_k<<<dim3(1024 / 32, 4096 / 32), tb, 0, stream>>>(Wff2, Wff2_t, 4096, 1024);

    ln_k<<<4096, 256, 0, stream>>>(x, g1, beta1, h_bf);
    gemm_k<0, 0, 0, 1><<<dim3(3072 / 128, 4096 / 128), 256, 0, stream>>>(
        h_bf, Wqkv_t, nullptr, nullptr, qkv_bf, 4096, 3072, 1024);
    vtrans_k<<<dim3(32, 32), dim3(64, 4), 0, stream>>>(qkv_bf, vt);
    attn_k<<<dim3(32, 32), 256, 0, stream>>>(qkv_bf, vt, att_bf);
    gemm_k<1, 0, 1, 0><<<dim3(1024 / 128, 4096 / 128), 256, 0, stream>>>(
        att_bf, Wo_t, b_o, x, x2, 4096, 1024, 1024);
    ln_k<<<4096, 256, 0, stream>>>(x2, g2, beta2, h_bf);
    gemm_k<1, 1, 0, 1><<<dim3(4096 / 128, 4096 / 128), 256, 0, stream>>>(
        h_bf, Wff1_t, bff1, nullptr, ff1_bf, 4096, 4096, 1024);
    gemm_k<1, 0, 1, 0><<<dim3(1024 / 128, 4096 / 128), 256, 0, stream>>>(
        ff1_bf, Wff2_t, bff2, x2, (float*)d_out, 4096, 1024, 4096);
}

// Round 3
// 412.380 us; speedup vs baseline: 1.3206x; 1.3206x over previous
//
#include <hip/hip_runtime.h>
#include <hip/hip_bf16.h>
#include <stdint.h>

// ---------------------------------------------------------------------------
// TransformerDecoderBlock on MI355X (gfx950).  B=2, T=2048, C=1024, H=16, hd=64.
// R2: attention back to LDS-staged K/V (V pre-transposed -> uint4 staging),
//     128-row Q tiles; BM128/BN64 GEMM for the N=1024 GEMMs (2 blocks/CU).
// ---------------------------------------------------------------------------

typedef __attribute__((ext_vector_type(8))) short bf16x8;   // 8 bf16 in 4 VGPRs
typedef __attribute__((ext_vector_type(4))) float f32x4;

#define MFMA16(a, b, c) __builtin_amdgcn_mfma_f32_16x16x32_bf16((a), (b), (c), 0, 0, 0)

__device__ __forceinline__ void gload16(const void* g, void* l) {
    __builtin_amdgcn_global_load_lds(
        (const __attribute__((address_space(1))) char*)g,
        (__attribute__((address_space(3))) char*)l, 16, 0, 0);
}

// --------------------------- transpose + fp32->bf16 ------------------------
__global__ __launch_bounds__(256) void tconv_k(const float* __restrict__ in,
                                               __hip_bfloat16* __restrict__ out,
                                               int K, int N) {
    __shared__ float tile[32][33];
    const int n0 = blockIdx.x * 32, k0 = blockIdx.y * 32;
    const int tx = threadIdx.x, ty = threadIdx.y;   // block (32, 8)
    for (int i = ty; i < 32; i += 8)
        tile[i][tx] = in[(size_t)(k0 + i) * N + n0 + tx];
    __syncthreads();
    for (int i = ty; i < 32; i += 8)
        out[(size_t)(n0 + i) * K + k0 + tx] = __float2bfloat16(tile[tx][i]);
}

// --------------------------------- layernorm -------------------------------
__global__ __launch_bounds__(256) void ln_k(const float* __restrict__ x,
                                            const float* __restrict__ g,
                                            const float* __restrict__ beta,
                                            __hip_bfloat16* __restrict__ out) {
    const int row = blockIdx.x;
    const int tid = threadIdx.x;
    float4 v = ((const float4*)(x + (size_t)row * 1024))[tid];
    float s  = v.x + v.y + v.z + v.w;
    float s2 = v.x * v.x + v.y * v.y + v.z * v.z + v.w * v.w;
    for (int off = 1; off < 64; off <<= 1) {
        s  += __shfl_xor(s,  off, 64);
        s2 += __shfl_xor(s2, off, 64);
    }
    __shared__ float ss[4], ss2[4];
    const int w = tid >> 6, lane = tid & 63;
    if (lane == 0) { ss[w] = s; ss2[w] = s2; }
    __syncthreads();
    s  = ss[0] + ss[1] + ss[2] + ss[3];
    s2 = ss2[0] + ss2[1] + ss2[2] + ss2[3];
    const float mu  = s * (1.0f / 1024.0f);
    const float var = s2 * (1.0f / 1024.0f) - mu * mu;
    const float rs  = rsqrtf(var + 1e-5f);
    float4 gv = ((const float4*)g)[tid];
    float4 bv = ((const float4*)beta)[tid];
    __hip_bfloat16* o = out + (size_t)row * 1024 + tid * 4;
    o[0] = __float2bfloat16((v.x - mu) * rs * gv.x + bv.x);
    o[1] = __float2bfloat16((v.y - mu) * rs * gv.y + bv.y);
    o[2] = __float2bfloat16((v.z - mu) * rs * gv.z + bv.z);
    o[3] = __float2bfloat16((v.w - mu) * rs * gv.w + bv.w);
}

// ------------------------- GEMM, BM=128 BN=128 BK=32 ------------------------
// m97 structure: global_load_lds w=16, XOR-swizzled LDS chunks.
template <int BIAS, int RELU, int RESID, int OUTBF>
__global__ __launch_bounds__(256, 3) void gemm_k(const __hip_bfloat16* __restrict__ A,
                                                 const __hip_bfloat16* __restrict__ Bt,
                                                 const float* __restrict__ bias,
                                                 const float* __restrict__ resid,
                                                 void* __restrict__ out,
                                                 int M, int N, int K) {
    __align__(16) __shared__ __hip_bfloat16 As[128 * 32];
    __align__(16) __shared__ __hip_bfloat16 Bs[128 * 32];

    const int tid  = threadIdx.x;
    const int lane = tid & 63, w = tid >> 6;
    const int wm = w >> 1, wn = w & 1;
    const int m0 = blockIdx.y * 128, n0 = blockIdx.x * 128;
    const int l16 = lane & 15, quad = lane >> 4;

    const int r0 = w * 16 + (lane >> 2);
    const int c0 = ((lane & 3) - ((r0 >> 1) & 3)) & 3;
    const int r1 = 64 + r0;
    const int c1 = ((lane & 3) - ((r1 >> 1) & 3)) & 3;
    const __hip_bfloat16* ga0 = A  + (size_t)(m0 + r0) * K + c0 * 8;
    const __hip_bfloat16* ga1 = A  + (size_t)(m0 + r1) * K + c1 * 8;
    const __hip_bfloat16* gb0 = Bt + (size_t)(n0 + r0) * K + c0 * 8;
    const __hip_bfloat16* gb1 = Bt + (size_t)(n0 + r1) * K + c1 * 8;

    int offA[4], offB[4];
#pragma unroll
    for (int t = 0; t < 4; t++) {
        const int rA = wm * 64 + t * 16 + l16;
        offA[t] = (rA * 4 + ((quad + ((rA >> 1) & 3)) & 3)) * 16;
        const int rB = wn * 64 + t * 16 + l16;
        offB[t] = (rB * 4 + ((quad + ((rB >> 1) & 3)) & 3)) * 16;
    }

    f32x4 acc[4][4] = {};

    for (int k0 = 0; k0 < K; k0 += 32) {
        __syncthreads();
        gload16(ga0, As + w * 512);
        gload16(ga1, As + 2048 + w * 512);
        gload16(gb0, Bs + w * 512);
        gload16(gb1, Bs + 2048 + w * 512);
        ga0 += 32; ga1 += 32; gb0 += 32; gb1 += 32;
        __syncthreads();

        bf16x8 af[4], bfr[4];
#pragma unroll
        for (int t = 0; t < 4; t++) {
            af[t]  = *(const bf16x8*)((const char*)As + offA[t]);
            bfr[t] = *(const bf16x8*)((const char*)Bs + offB[t]);
        }
#pragma unroll
        for (int mt = 0; mt < 4; mt++)
#pragma unroll
            for (int nt = 0; nt < 4; nt++)
                acc[mt][nt] = MFMA16(af[mt], bfr[nt], acc[mt][nt]);
    }

#pragma unroll
    for (int mt = 0; mt < 4; mt++)
#pragma unroll
        for (int nt = 0; nt < 4; nt++) {
            const int row = m0 + wm * 64 + mt * 16 + quad * 4;
            const int col = n0 + wn * 64 + nt * 16 + l16;
            const float bv = BIAS ? bias[col] : 0.0f;
#pragma unroll
            for (int r = 0; r < 4; r++) {
                float v = acc[mt][nt][r] + bv;
                if (RELU) v = v > 0.0f ? v : 0.0f;
                const size_t idx = (size_t)(row + r) * N + col;
                if (RESID) v += resid[idx];
                if (OUTBF) ((__hip_bfloat16*)out)[idx] = __float2bfloat16(v);
                else       ((float*)out)[idx] = v;
            }
        }
}

// ------------------------- GEMM, BM=128 BN=64 BK=32 -------------------------
// For N=1024 outputs: 512 blocks -> >=2 blocks/CU.  Wave tile 64x32.
template <int BIAS, int RELU, int RESID, int OUTBF>
__global__ __launch_bounds__(256, 3) void gemm64_k(const __hip_bfloat16* __restrict__ A,
                                                   const __hip_bfloat16* __restrict__ Bt,
                                                   const float* __restrict__ bias,
                                                   const float* __restrict__ resid,
                                                   void* __restrict__ out,
                                                   int M, int N, int K) {
    __align__(16) __shared__ __hip_bfloat16 As[128 * 32];
    __align__(16) __shared__ __hip_bfloat16 Bs[64 * 32];

    const int tid  = threadIdx.x;
    const int lane = tid & 63, w = tid >> 6;
    const int wm = w >> 1, wn = w & 1;
    const int m0 = blockIdx.y * 128, n0 = blockIdx.x * 64;
    const int l16 = lane & 15, quad = lane >> 4;

    const int r0 = w * 16 + (lane >> 2);
    const int c0 = ((lane & 3) - ((r0 >> 1) & 3)) & 3;
    const int r1 = 64 + r0;
    const int c1 = ((lane & 3) - ((r1 >> 1) & 3)) & 3;
    const __hip_bfloat16* ga0 = A  + (size_t)(m0 + r0) * K + c0 * 8;
    const __hip_bfloat16* ga1 = A  + (size_t)(m0 + r1) * K + c1 * 8;
    const __hip_bfloat16* gb0 = Bt + (size_t)(n0 + r0) * K + c0 * 8;

    int offA[4], offB[2];
#pragma unroll
    for (int t = 0; t < 4; t++) {
        const int rA = wm * 64 + t * 16 + l16;
        offA[t] = (rA * 4 + ((quad + ((rA >> 1) & 3)) & 3)) * 16;
    }
#pragma unroll
    for (int t = 0; t < 2; t++) {
        const int rB = wn * 32 + t * 16 + l16;
        offB[t] = (rB * 4 + ((quad + ((rB >> 1) & 3)) & 3)) * 16;
    }

    f32x4 acc[4][2] = {};

    for (int k0 = 0; k0 < K; k0 += 32) {
        __syncthreads();
        gload16(ga0, As + w * 512);
        gload16(ga1, As + 2048 + w * 512);
        gload16(gb0, Bs + w * 512);
        ga0 += 32; ga1 += 32; gb0 += 32;
        __syncthreads();

        bf16x8 af[4], bfr[2];
#pragma unroll
        for (int t = 0; t < 4; t++)
            af[t] = *(const bf16x8*)((const char*)As + offA[t]);
#pragma unroll
        for (int t = 0; t < 2; t++)
            bfr[t] = *(const bf16x8*)((const char*)Bs + offB[t]);
#pragma unroll
        for (int mt = 0; mt < 4; mt++)
#pragma unroll
            for (int nt = 0; nt < 2; nt++)
                acc[mt][nt] = MFMA16(af[mt], bfr[nt], acc[mt][nt]);
    }

#pragma unroll
    for (int mt = 0; mt < 4; mt++)
#pragma unroll
        for (int nt = 0; nt < 2; nt++) {
            const int row = m0 + wm * 64 + mt * 16 + quad * 4;
            const int col = n0 + wn * 32 + nt * 16 + l16;
            const float bv = BIAS ? bias[col] : 0.0f;
#pragma unroll
            for (int r = 0; r < 4; r++) {
                float v = acc[mt][nt][r] + bv;
                if (RELU) v = v > 0.0f ? v : 0.0f;
                const size_t idx = (size_t)(row + r) * N + col;
                if (RESID) v += resid[idx];
                if (OUTBF) ((__hip_bfloat16*)out)[idx] = __float2bfloat16(v);
                else       ((float*)out)[idx] = v;
            }
        }
}

// ----------------------- V transpose: qkv -> Vt[bh][d][T] -------------------
__global__ __launch_bounds__(256) void vtrans_k(const __hip_bfloat16* __restrict__ qkv,
                                                __hip_bfloat16* __restrict__ vt) {
    const int T = 2048, C3 = 3072;
    const int bh = blockIdx.y, b = bh >> 4, h = bh & 15;
    const int t0 = blockIdx.x * 64;
    const int tx = threadIdx.x, ty = threadIdx.y;   // block (64, 4)
    __shared__ __hip_bfloat16 tile[64][65];
#pragma unroll
    for (int j = 0; j < 16; j++) {
        const int tl = ty * 16 + j;
        tile[tl][tx] = qkv[(size_t)(b * T + t0 + tl) * C3 + 2048 + h * 64 + tx];
    }
    __syncthreads();
#pragma unroll
    for (int j = 0; j < 16; j++) {
        const int d = ty * 16 + j;
        vt[((size_t)bh * 64 + d) * 2048 + t0 + tx] = tile[tx][d];
    }
}

// ------------------------------ flash attention -----------------------------
// Block = (bh, 128 q rows); 4 waves x 32 q rows (2 m-tiles each).
// K and V^T tiles staged in LDS via uint4 (V from pre-transposed vt).
__global__ __launch_bounds__(256, 3) void attn_k(const __hip_bfloat16* __restrict__ qkv,
                                                 const __hip_bfloat16* __restrict__ vt,
                                                 __hip_bfloat16* __restrict__ outp) {
    const int T = 2048, C3 = 3072;
    const int bh = blockIdx.x, b = bh >> 4, h = bh & 15;
    const int j = 15 - blockIdx.y;            // heavy q-tiles dispatched first
    const int q0 = j * 128;
    const int tid = threadIdx.x, lane = tid & 63, w = tid >> 6;
    const int l16 = lane & 15, quad = lane >> 4;

    __align__(16) __shared__ __hip_bfloat16 Ks[64 * 72];     // [key][d]
    __align__(16) __shared__ __hip_bfloat16 Vs[64 * 72];     // [d][key]
    __align__(16) __shared__ __hip_bfloat16 Pw[4][32 * 72];  // per-wave P [qrow][key]

    // Q fragments: wave w owns q rows q0 + w*32 .. +31 (2 m-tiles)
    bf16x8 qf[2][2];
#pragma unroll
    for (int mt = 0; mt < 2; mt++) {
        const __hip_bfloat16* qp =
            qkv + (size_t)(b * T + q0 + w * 32 + mt * 16 + l16) * C3 + h * 64;
        qf[mt][0] = *(const bf16x8*)(qp + quad * 8);
        qf[mt][1] = *(const bf16x8*)(qp + 32 + quad * 8);
    }

    f32x4 oacc[2][4] = {};
    float mrow[2][4], lrow[2][4];
#pragma unroll
    for (int mt = 0; mt < 2; mt++)
#pragma unroll
        for (int r = 0; r < 4; r++) { mrow[mt][r] = -3e38f; lrow[mt][r] = 0.0f; }
    const float sc = 0.125f * 1.44269504f;    // exp2 domain

    const int srow  = tid >> 2;               // 0..63
    const int spart = tid & 3;                // 16-element chunk
    const __hip_bfloat16* kgb = qkv + (size_t)(b * T) * C3 + 1024 + h * 64 + spart * 16;
    const __hip_bfloat16* vgb = vt + ((size_t)bh * 64 + srow) * 2048 + spart * 16;
    __hip_bfloat16* ksd = Ks + srow * 72 + spart * 16;
    __hip_bfloat16* vsd = Vs + srow * 72 + spart * 16;

    const int ktend = 2 * j + 1;
    const int ktmax = 2 * j + (w >> 1);       // waves 0,1 stop one tile earlier

    for (int kt = 0; kt <= ktend; kt++) {
        __syncthreads();
        {
            const uint4* kg = (const uint4*)(kgb + (size_t)(kt * 64 + srow) * C3);
            ((uint4*)ksd)[0] = kg[0];
            ((uint4*)ksd)[1] = kg[1];
            const uint4* vg = (const uint4*)(vgb + kt * 64);
            ((uint4*)vsd)[0] = vg[0];
            ((uint4*)vsd)[1] = vg[1];
        }
        __syncthreads();
        if (kt > ktmax) continue;             // wave-uniform

        // ---- S = Q K^T ----
        f32x4 s[2][4];
#pragma unroll
        for (int nt = 0; nt < 4; nt++) {
            bf16x8 kf0 = *(const bf16x8*)(Ks + (nt * 16 + l16) * 72 + quad * 8);
            bf16x8 kf1 = *(const bf16x8*)(Ks + (nt * 16 + l16) * 72 + 32 + quad * 8);
#pragma unroll
            for (int mt = 0; mt < 2; mt++) {
                f32x4 z = {};
                z = MFMA16(qf[mt][0], kf0, z);
                z = MFMA16(qf[mt][1], kf1, z);
                s[mt][nt] = z;
            }
        }

        // ---- scale (+ diagonal mask) + tile rowmax ----
        float mt4[2][4];
#pragma unroll
        for (int mt = 0; mt < 2; mt++)
#pragma unroll
            for (int r = 0; r < 4; r++) mt4[mt][r] = -3e38f;
        const bool diag = (kt == ktmax);
#pragma unroll
        for (int nt = 0; nt < 4; nt++) {
            const int col = kt * 64 + nt * 16 + l16;
#pragma unroll
            for (int mt = 0; mt < 2; mt++)
#pragma unroll
                for (int r = 0; r < 4; r++) {
                    const int row = q0 + w * 32 + mt * 16 + quad * 4 + r;
                    float v = s[mt][nt][r] * sc;
                    if (diag && col > row) v = -3e38f;
                    s[mt][nt][r] = v;
                    mt4[mt][r] = fmaxf(mt4[mt][r], v);
                }
        }
#pragma unroll
        for (int off = 1; off < 16; off <<= 1)
#pragma unroll
            for (int mt = 0; mt < 2; mt++)
#pragma unroll
                for (int r = 0; r < 4; r++)
                    mt4[mt][r] = fmaxf(mt4[mt][r], __shfl_xor(mt4[mt][r], off, 64));

        float alpha[2][4], ls[2][4];
#pragma unroll
        for (int mt = 0; mt < 2; mt++)
#pragma unroll
            for (int r = 0; r < 4; r++) {
                const float mnew = fmaxf(mrow[mt][r], mt4[mt][r]);
                alpha[mt][r] = exp2f(mrow[mt][r] - mnew);
                mrow[mt][r] = mnew;
                ls[mt][r] = 0.0f;
            }
#pragma unroll
        for (int nt = 0; nt < 4; nt++)
#pragma unroll
            for (int mt = 0; mt < 2; mt++)
#pragma unroll
                for (int r = 0; r < 4; r++) {
                    const float p = exp2f(s[mt][nt][r] - mrow[mt][r]);
                    ls[mt][r] += p;
                    Pw[w][(mt * 16 + quad * 4 + r) * 72 + nt * 16 + l16] =
                        __float2bfloat16(p);
                }
#pragma unroll
        for (int off = 1; off < 16; off <<= 1)
#pragma unroll
            for (int mt = 0; mt < 2; mt++)
#pragma unroll
                for (int r = 0; r < 4; r++)
                    ls[mt][r] += __shfl_xor(ls[mt][r], off, 64);
#pragma unroll
        for (int mt = 0; mt < 2; mt++)
#pragma unroll
            for (int r = 0; r < 4; r++)
                lrow[mt][r] = lrow[mt][r] * alpha[mt][r] + ls[mt][r];
#pragma unroll
        for (int mt = 0; mt < 2; mt++)
#pragma unroll
            for (int dt = 0; dt < 4; dt++)
#pragma unroll
                for (int r = 0; r < 4; r++)
                    oacc[mt][dt][r] *= alpha[mt][r];

        asm volatile("s_waitcnt lgkmcnt(0)" ::: "memory");  // own-wave P visible

        // ---- O += P @ V ----
        bf16x8 pf[2][2];
#pragma unroll
        for (int mt = 0; mt < 2; mt++) {
            pf[mt][0] = *(const bf16x8*)(&Pw[w][(mt * 16 + l16) * 72 + quad * 8]);
            pf[mt][1] = *(const bf16x8*)(&Pw[w][(mt * 16 + l16) * 72 + 32 + quad * 8]);
        }
#pragma unroll
        for (int dt = 0; dt < 4; dt++) {
            bf16x8 vf0 = *(const bf16x8*)(Vs + (dt * 16 + l16) * 72 + quad * 8);
            bf16x8 vf1 = *(const bf16x8*)(Vs + (dt * 16 + l16) * 72 + 32 + quad * 8);
#pragma unroll
            for (int mt = 0; mt < 2; mt++) {
                oacc[mt][dt] = MFMA16(pf[mt][0], vf0, oacc[mt][dt]);
                oacc[mt][dt] = MFMA16(pf[mt][1], vf1, oacc[mt][dt]);
            }
        }
    }

#pragma unroll
    for (int mt = 0; mt < 2; mt++) {
        float rl[4];
#pragma unroll
        for (int r = 0; r < 4; r++) rl[r] = 1.0f / lrow[mt][r];
#pragma unroll
        for (int dt = 0; dt < 4; dt++)
#pragma unroll
            for (int r = 0; r < 4; r++) {
                const int row = q0 + w * 32 + mt * 16 + quad * 4 + r;
                outp[(size_t)(b * T + row) * 1024 + h * 64 + dt * 16 + l16] =
                    __float2bfloat16(oacc[mt][dt][r] * rl[r]);
            }
    }
}

// --------------------------------- launcher --------------------------------
extern "C" void kernel_launch(void* const* d_in, const int* in_sizes, int n_in,
                              void* d_out, int out_size, void* d_ws, size_t ws_size,
                              hipStream_t stream) {
    const float* x     = (const float*)d_in[0];
    const float* Wqkv  = (const float*)d_in[1];
    const float* Wo    = (const float*)d_in[2];
    const float* b_o   = (const float*)d_in[3];
    const float* g1    = (const float*)d_in[4];
    const float* beta1 = (const float*)d_in[5];
    const float* g2    = (const float*)d_in[6];
    const float* beta2 = (const float*)d_in[7];
    const float* Wff1  = (const float*)d_in[8];
    const float* bff1  = (const float*)d_in[9];
    const float* Wff2  = (const float*)d_in[10];
    const float* bff2  = (const float*)d_in[11];

    char* ws = (char*)d_ws;
    size_t off = 0;
    auto alloc = [&](size_t bytes) {
        void* p = ws + off;
        off += (bytes + 255) & ~(size_t)255;
        return p;
    };
    __hip_bfloat16* Wqkv_t = (__hip_bfloat16*)alloc(3072ULL * 1024 * 2);
    __hip_bfloat16* Wo_t   = (__hip_bfloat16*)alloc(1024ULL * 1024 * 2);
    __hip_bfloat16* Wff1_t = (__hip_bfloat16*)alloc(4096ULL * 1024 * 2);
    __hip_bfloat16* Wff2_t = (__hip_bfloat16*)alloc(1024ULL * 4096 * 2);
    __hip_bfloat16* h_bf   = (__hip_bfloat16*)alloc(4096ULL * 1024 * 2);
    __hip_bfloat16* qkv_bf = (__hip_bfloat16*)alloc(4096ULL * 3072 * 2);
    __hip_bfloat16* att_bf = (__hip_bfloat16*)alloc(4096ULL * 1024 * 2);
    float*          x2     = (float*)alloc(4096ULL * 1024 * 4);
    __hip_bfloat16* ff1_bf = qkv_bf;              // dead by FF time
    __hip_bfloat16* vt     = (__hip_bfloat16*)x2; // dead before Wo-gemm writes x2

    const dim3 tb(32, 8);
    tconv_k<<<dim3(3072 / 32, 1024 / 32), tb, 0, stream>>>(Wqkv, Wqkv_t, 1024, 3072);
    tconv_k<<<dim3(1024 / 32, 1024 / 32), tb, 0, stream>>>(Wo,   Wo_t,   1024, 1024);
    tconv_k<<<dim3(4096 / 32, 1024 / 32), tb, 0, stream>>>(Wff1, Wff1_t, 1024, 4096);
    tconv_k<<<dim3(1024 / 32, 4096 / 32), tb, 0, stream>>>(Wff2, Wff2_t, 4096, 1024);

    ln_k<<<4096, 256, 0, stream>>>(x, g1, beta1, h_bf);
    gemm_k<0, 0, 0, 1><<<dim3(3072 / 128, 4096 / 128), 256, 0, stream>>>(
        h_bf, Wqkv_t, nullptr, nullptr, qkv_bf, 4096, 3072, 1024);
    vtrans_k<<<dim3(32, 32), dim3(64, 4), 0, stream>>>(qkv_bf, vt);
    attn_k<<<dim3(32, 16), 256, 0, stream>>>(qkv_bf, vt, att_bf);
    gemm64_k<1, 0, 1, 0><<<dim3(1024 / 64, 4096 / 128), 256, 0, stream>>>(
        att_bf, Wo_t, b_o, x, x2, 4096, 1024, 1024);
    ln_k<<<4096, 256, 0, stream>>>(x2, g2, beta2, h_bf);
    gemm_k<1, 1, 0, 1><<<dim3(4096 / 128, 4096 / 128), 256, 0, stream>>>(
        h_bf, Wff1_t, bff1, nullptr, ff1_bf, 4096, 4096, 1024);
    gemm64_k<1, 0, 1, 0><<<dim3(1024 / 64, 4096 / 128), 256, 0, stream>>>(
        ff1_bf, Wff2_t, bff2, x2, (float*)d_out, 4096, 1024, 4096);
}

// Round 5
// 384.299 us; speedup vs baseline: 1.4171x; 1.0731x over previous
//
#include <hip/hip_runtime.h>
#include <hip/hip_bf16.h>
#include <stdint.h>

// ---------------------------------------------------------------------------
// TransformerDecoderBlock on MI355X (gfx950).  B=2, T=2048, C=1024, H=16, hd=64.
// R4: fix R3's diagonal-mask bug (row must include w*16).  Attention =
//     fixed-max flash, deferred l-reduce, double-buffered K/V, one barrier/iter.
// ---------------------------------------------------------------------------

typedef __attribute__((ext_vector_type(8))) short bf16x8;   // 8 bf16 in 4 VGPRs
typedef __attribute__((ext_vector_type(4))) float f32x4;

#define MFMA16(a, b, c) __builtin_amdgcn_mfma_f32_16x16x32_bf16((a), (b), (c), 0, 0, 0)

__device__ __forceinline__ void gload16(const void* g, void* l) {
    __builtin_amdgcn_global_load_lds(
        (const __attribute__((address_space(1))) char*)g,
        (__attribute__((address_space(3))) char*)l, 16, 0, 0);
}

// --------------------------- transpose + fp32->bf16 ------------------------
__global__ __launch_bounds__(256) void tconv_k(const float* __restrict__ in,
                                               __hip_bfloat16* __restrict__ out,
                                               int K, int N) {
    __shared__ float tile[32][33];
    const int n0 = blockIdx.x * 32, k0 = blockIdx.y * 32;
    const int tx = threadIdx.x, ty = threadIdx.y;   // block (32, 8)
    for (int i = ty; i < 32; i += 8)
        tile[i][tx] = in[(size_t)(k0 + i) * N + n0 + tx];
    __syncthreads();
    for (int i = ty; i < 32; i += 8)
        out[(size_t)(n0 + i) * K + k0 + tx] = __float2bfloat16(tile[tx][i]);
}

// --------------------------------- layernorm -------------------------------
__global__ __launch_bounds__(256) void ln_k(const float* __restrict__ x,
                                            const float* __restrict__ g,
                                            const float* __restrict__ beta,
                                            __hip_bfloat16* __restrict__ out) {
    const int row = blockIdx.x;
    const int tid = threadIdx.x;
    float4 v = ((const float4*)(x + (size_t)row * 1024))[tid];
    float s  = v.x + v.y + v.z + v.w;
    float s2 = v.x * v.x + v.y * v.y + v.z * v.z + v.w * v.w;
    for (int off = 1; off < 64; off <<= 1) {
        s  += __shfl_xor(s,  off, 64);
        s2 += __shfl_xor(s2, off, 64);
    }
    __shared__ float ss[4], ss2[4];
    const int w = tid >> 6, lane = tid & 63;
    if (lane == 0) { ss[w] = s; ss2[w] = s2; }
    __syncthreads();
    s  = ss[0] + ss[1] + ss[2] + ss[3];
    s2 = ss2[0] + ss2[1] + ss2[2] + ss2[3];
    const float mu  = s * (1.0f / 1024.0f);
    const float var = s2 * (1.0f / 1024.0f) - mu * mu;
    const float rs  = rsqrtf(var + 1e-5f);
    float4 gv = ((const float4*)g)[tid];
    float4 bv = ((const float4*)beta)[tid];
    __hip_bfloat16* o = out + (size_t)row * 1024 + tid * 4;
    o[0] = __float2bfloat16((v.x - mu) * rs * gv.x + bv.x);
    o[1] = __float2bfloat16((v.y - mu) * rs * gv.y + bv.y);
    o[2] = __float2bfloat16((v.z - mu) * rs * gv.z + bv.z);
    o[3] = __float2bfloat16((v.w - mu) * rs * gv.w + bv.w);
}

// ------------------------- GEMM, BM=128 BN=128 BK=32 ------------------------
template <int BIAS, int RELU, int RESID, int OUTBF>
__global__ __launch_bounds__(256, 3) void gemm_k(const __hip_bfloat16* __restrict__ A,
                                                 const __hip_bfloat16* __restrict__ Bt,
                                                 const float* __restrict__ bias,
                                                 const float* __restrict__ resid,
                                                 void* __restrict__ out,
                                                 int M, int N, int K) {
    __align__(16) __shared__ __hip_bfloat16 As[128 * 32];
    __align__(16) __shared__ __hip_bfloat16 Bs[128 * 32];

    const int tid  = threadIdx.x;
    const int lane = tid & 63, w = tid >> 6;
    const int wm = w >> 1, wn = w & 1;
    const int m0 = blockIdx.y * 128, n0 = blockIdx.x * 128;
    const int l16 = lane & 15, quad = lane >> 4;

    const int r0 = w * 16 + (lane >> 2);
    const int c0 = ((lane & 3) - ((r0 >> 1) & 3)) & 3;
    const int r1 = 64 + r0;
    const int c1 = ((lane & 3) - ((r1 >> 1) & 3)) & 3;
    const __hip_bfloat16* ga0 = A  + (size_t)(m0 + r0) * K + c0 * 8;
    const __hip_bfloat16* ga1 = A  + (size_t)(m0 + r1) * K + c1 * 8;
    const __hip_bfloat16* gb0 = Bt + (size_t)(n0 + r0) * K + c0 * 8;
    const __hip_bfloat16* gb1 = Bt + (size_t)(n0 + r1) * K + c1 * 8;

    int offA[4], offB[4];
#pragma unroll
    for (int t = 0; t < 4; t++) {
        const int rA = wm * 64 + t * 16 + l16;
        offA[t] = (rA * 4 + ((quad + ((rA >> 1) & 3)) & 3)) * 16;
        const int rB = wn * 64 + t * 16 + l16;
        offB[t] = (rB * 4 + ((quad + ((rB >> 1) & 3)) & 3)) * 16;
    }

    f32x4 acc[4][4] = {};

    for (int k0 = 0; k0 < K; k0 += 32) {
        __syncthreads();
        gload16(ga0, As + w * 512);
        gload16(ga1, As + 2048 + w * 512);
        gload16(gb0, Bs + w * 512);
        gload16(gb1, Bs + 2048 + w * 512);
        ga0 += 32; ga1 += 32; gb0 += 32; gb1 += 32;
        __syncthreads();

        bf16x8 af[4], bfr[4];
#pragma unroll
        for (int t = 0; t < 4; t++) {
            af[t]  = *(const bf16x8*)((const char*)As + offA[t]);
            bfr[t] = *(const bf16x8*)((const char*)Bs + offB[t]);
        }
#pragma unroll
        for (int mt = 0; mt < 4; mt++)
#pragma unroll
            for (int nt = 0; nt < 4; nt++)
                acc[mt][nt] = MFMA16(af[mt], bfr[nt], acc[mt][nt]);
    }

#pragma unroll
    for (int mt = 0; mt < 4; mt++)
#pragma unroll
        for (int nt = 0; nt < 4; nt++) {
            const int row = m0 + wm * 64 + mt * 16 + quad * 4;
            const int col = n0 + wn * 64 + nt * 16 + l16;
            const float bv = BIAS ? bias[col] : 0.0f;
#pragma unroll
            for (int r = 0; r < 4; r++) {
                float v = acc[mt][nt][r] + bv;
                if (RELU) v = v > 0.0f ? v : 0.0f;
                const size_t idx = (size_t)(row + r) * N + col;
                if (RESID) v += resid[idx];
                if (OUTBF) ((__hip_bfloat16*)out)[idx] = __float2bfloat16(v);
                else       ((float*)out)[idx] = v;
            }
        }
}

// ------------------------- GEMM, BM=128 BN=64 BK=32 -------------------------
template <int BIAS, int RELU, int RESID, int OUTBF>
__global__ __launch_bounds__(256, 3) void gemm64_k(const __hip_bfloat16* __restrict__ A,
                                                   const __hip_bfloat16* __restrict__ Bt,
                                                   const float* __restrict__ bias,
                                                   const float* __restrict__ resid,
                                                   void* __restrict__ out,
                                                   int M, int N, int K) {
    __align__(16) __shared__ __hip_bfloat16 As[128 * 32];
    __align__(16) __shared__ __hip_bfloat16 Bs[64 * 32];

    const int tid  = threadIdx.x;
    const int lane = tid & 63, w = tid >> 6;
    const int wm = w >> 1, wn = w & 1;
    const int m0 = blockIdx.y * 128, n0 = blockIdx.x * 64;
    const int l16 = lane & 15, quad = lane >> 4;

    const int r0 = w * 16 + (lane >> 2);
    const int c0 = ((lane & 3) - ((r0 >> 1) & 3)) & 3;
    const int r1 = 64 + r0;
    const int c1 = ((lane & 3) - ((r1 >> 1) & 3)) & 3;
    const __hip_bfloat16* ga0 = A  + (size_t)(m0 + r0) * K + c0 * 8;
    const __hip_bfloat16* ga1 = A  + (size_t)(m0 + r1) * K + c1 * 8;
    const __hip_bfloat16* gb0 = Bt + (size_t)(n0 + r0) * K + c0 * 8;

    int offA[4], offB[2];
#pragma unroll
    for (int t = 0; t < 4; t++) {
        const int rA = wm * 64 + t * 16 + l16;
        offA[t] = (rA * 4 + ((quad + ((rA >> 1) & 3)) & 3)) * 16;
    }
#pragma unroll
    for (int t = 0; t < 2; t++) {
        const int rB = wn * 32 + t * 16 + l16;
        offB[t] = (rB * 4 + ((quad + ((rB >> 1) & 3)) & 3)) * 16;
    }

    f32x4 acc[4][2] = {};

    for (int k0 = 0; k0 < K; k0 += 32) {
        __syncthreads();
        gload16(ga0, As + w * 512);
        gload16(ga1, As + 2048 + w * 512);
        gload16(gb0, Bs + w * 512);
        ga0 += 32; ga1 += 32; gb0 += 32;
        __syncthreads();

        bf16x8 af[4], bfr[2];
#pragma unroll
        for (int t = 0; t < 4; t++)
            af[t] = *(const bf16x8*)((const char*)As + offA[t]);
#pragma unroll
        for (int t = 0; t < 2; t++)
            bfr[t] = *(const bf16x8*)((const char*)Bs + offB[t]);
#pragma unroll
        for (int mt = 0; mt < 4; mt++)
#pragma unroll
            for (int nt = 0; nt < 2; nt++)
                acc[mt][nt] = MFMA16(af[mt], bfr[nt], acc[mt][nt]);
    }

#pragma unroll
    for (int mt = 0; mt < 4; mt++)
#pragma unroll
        for (int nt = 0; nt < 2; nt++) {
            const int row = m0 + wm * 64 + mt * 16 + quad * 4;
            const int col = n0 + wn * 32 + nt * 16 + l16;
            const float bv = BIAS ? bias[col] : 0.0f;
#pragma unroll
            for (int r = 0; r < 4; r++) {
                float v = acc[mt][nt][r] + bv;
                if (RELU) v = v > 0.0f ? v : 0.0f;
                const size_t idx = (size_t)(row + r) * N + col;
                if (RESID) v += resid[idx];
                if (OUTBF) ((__hip_bfloat16*)out)[idx] = __float2bfloat16(v);
                else       ((float*)out)[idx] = v;
            }
        }
}

// ----------------------- V transpose: qkv -> Vt[bh][d][T] -------------------
__global__ __launch_bounds__(256) void vtrans_k(const __hip_bfloat16* __restrict__ qkv,
                                                __hip_bfloat16* __restrict__ vt) {
    const int T = 2048, C3 = 3072;
    const int bh = blockIdx.y, b = bh >> 4, h = bh & 15;
    const int t0 = blockIdx.x * 64;
    const int tx = threadIdx.x, ty = threadIdx.y;   // block (64, 4)
    __shared__ __hip_bfloat16 tile[64][65];
#pragma unroll
    for (int j = 0; j < 16; j++) {
        const int tl = ty * 16 + j;
        tile[tl][tx] = qkv[(size_t)(b * T + t0 + tl) * C3 + 2048 + h * 64 + tx];
    }
    __syncthreads();
#pragma unroll
    for (int j = 0; j < 16; j++) {
        const int d = ty * 16 + j;
        vt[((size_t)bh * 64 + d) * 2048 + t0 + tx] = tile[tx][d];
    }
}

// ------------------------------ flash attention -----------------------------
// Fixed-max softmax (scores bounded; softmax shift-invariant).  Block =
// (bh, 64 q rows); 4 waves x 16 q rows.  Double-buffered K/V, one barrier/iter.
__global__ __launch_bounds__(256, 3) void attn_k(const __hip_bfloat16* __restrict__ qkv,
                                                 const __hip_bfloat16* __restrict__ vt,
                                                 __hip_bfloat16* __restrict__ outp) {
    const int T = 2048, C3 = 3072;
    const int bh = blockIdx.y, b = bh >> 4, h = bh & 15;
    const int qt = 31 - blockIdx.x;           // heavy q-tiles dispatched first
    const int q0 = qt * 64;
    const int tid = threadIdx.x, lane = tid & 63, w = tid >> 6;
    const int l16 = lane & 15, quad = lane >> 4;

    __align__(16) __shared__ __hip_bfloat16 Ks[2][64 * 72];   // [key][d]
    __align__(16) __shared__ __hip_bfloat16 Vs[2][64 * 72];   // [d][key]
    __align__(16) __shared__ __hip_bfloat16 Pw[4][16 * 72];   // per-wave P

    // Q fragments, pre-scaled by log2e/8 (folds softmax scale into exp2 domain)
    const float sc = 0.125f * 1.44269504f;
    bf16x8 qf0, qf1;
    {
        const __hip_bfloat16* qp =
            qkv + (size_t)(b * T + q0 + w * 16 + l16) * C3 + h * 64;
        bf16x8 a = *(const bf16x8*)(qp + quad * 8);
        bf16x8 c = *(const bf16x8*)(qp + 32 + quad * 8);
#pragma unroll
        for (int i = 0; i < 8; i++) {
            union { unsigned int u; float f; } ua, uc;
            ua.u = ((unsigned int)(unsigned short)a[i]) << 16;
            uc.u = ((unsigned int)(unsigned short)c[i]) << 16;
            qf0[i] = (short)(__bfloat16_as_ushort(__float2bfloat16(ua.f * sc)));
            qf1[i] = (short)(__bfloat16_as_ushort(__float2bfloat16(uc.f * sc)));
        }
    }

    f32x4 oacc[4] = {};
    float lpart[4] = {0.0f, 0.0f, 0.0f, 0.0f};

    const int srow  = tid >> 2;               // 0..63
    const int spart = tid & 3;                // 16-element chunk
    const __hip_bfloat16* kg = qkv + (size_t)(b * T) * C3 + 1024 + h * 64 + spart * 16;
    const __hip_bfloat16* vg = vt + ((size_t)bh * 64 + srow) * 2048 + spart * 16;

    // preload tile 0 into registers
    uint4 kr0, kr1, vr0, vr1;
    {
        const uint4* kp = (const uint4*)(kg + (size_t)srow * C3);
        kr0 = kp[0]; kr1 = kp[1];
        const uint4* vp = (const uint4*)vg;
        vr0 = vp[0]; vr1 = vp[1];
    }

    for (int kt = 0; kt <= qt; kt++) {
        const int buf = kt & 1;
        {
            uint4* kd = (uint4*)(Ks[buf] + srow * 72 + spart * 16);
            kd[0] = kr0; kd[1] = kr1;
            uint4* vd = (uint4*)(Vs[buf] + srow * 72 + spart * 16);
            vd[0] = vr0; vd[1] = vr1;
        }
        if (kt < qt) {   // prefetch next tile (latency hidden by compute)
            const uint4* kp = (const uint4*)(kg + (size_t)((kt + 1) * 64 + srow) * C3);
            kr0 = kp[0]; kr1 = kp[1];
            const uint4* vp = (const uint4*)(vg + (kt + 1) * 64);
            vr0 = vp[0]; vr1 = vp[1];
        }
        __syncthreads();   // buf writes visible; prev iter's reads already done

        // ---- S = (Q*sc) K^T ----
        f32x4 s[4];
#pragma unroll
        for (int nt = 0; nt < 4; nt++) {
            bf16x8 kf0 = *(const bf16x8*)(Ks[buf] + (nt * 16 + l16) * 72 + quad * 8);
            bf16x8 kf1 = *(const bf16x8*)(Ks[buf] + (nt * 16 + l16) * 72 + 32 + quad * 8);
            f32x4 z = {};
            z = MFMA16(qf0, kf0, z);
            z = MFMA16(qf1, kf1, z);
            s[nt] = z;
        }

        // ---- p = exp2(s) (+ diagonal mask), accumulate l, write P ----
        const bool diag = (kt == qt);
        const int myrow = w * 16 + quad * 4;      // q-row within 64-row tile
#pragma unroll
        for (int nt = 0; nt < 4; nt++) {
            const int col = nt * 16 + l16;
#pragma unroll
            for (int r = 0; r < 4; r++) {
                float p = exp2f(s[nt][r]);
                if (diag && col > myrow + r) p = 0.0f;   // R4 FIX: include w*16
                lpart[r] += p;
                Pw[w][(quad * 4 + r) * 72 + col] = __float2bfloat16(p);
            }
        }

        asm volatile("s_waitcnt lgkmcnt(0)" ::: "memory");  // own-wave P visible

        // ---- O += P @ V ----
        bf16x8 pf0 = *(const bf16x8*)(&Pw[w][l16 * 72 + quad * 8]);
        bf16x8 pf1 = *(const bf16x8*)(&Pw[w][l16 * 72 + 32 + quad * 8]);
#pragma unroll
        for (int dt = 0; dt < 4; dt++) {
            bf16x8 vf0 = *(const bf16x8*)(Vs[buf] + (dt * 16 + l16) * 72 + quad * 8);
            bf16x8 vf1 = *(const bf16x8*)(Vs[buf] + (dt * 16 + l16) * 72 + 32 + quad * 8);
            oacc[dt] = MFMA16(pf0, vf0, oacc[dt]);
            oacc[dt] = MFMA16(pf1, vf1, oacc[dt]);
        }
    }

    // single deferred l-reduction across the 16 lanes sharing a quad-row
#pragma unroll
    for (int off = 1; off < 16; off <<= 1)
#pragma unroll
        for (int r = 0; r < 4; r++)
            lpart[r] += __shfl_xor(lpart[r], off, 64);

    float rl[4];
#pragma unroll
    for (int r = 0; r < 4; r++) rl[r] = 1.0f / lpart[r];
#pragma unroll
    for (int dt = 0; dt < 4; dt++)
#pragma unroll
        for (int r = 0; r < 4; r++) {
            const int row = q0 + w * 16 + quad * 4 + r;
            outp[(size_t)(b * T + row) * 1024 + h * 64 + dt * 16 + l16] =
                __float2bfloat16(oacc[dt][r] * rl[r]);
        }
}

// --------------------------------- launcher --------------------------------
extern "C" void kernel_launch(void* const* d_in, const int* in_sizes, int n_in,
                              void* d_out, int out_size, void* d_ws, size_t ws_size,
                              hipStream_t stream) {
    const float* x     = (const float*)d_in[0];
    const float* Wqkv  = (const float*)d_in[1];
    const float* Wo    = (const float*)d_in[2];
    const float* b_o   = (const float*)d_in[3];
    const float* g1    = (const float*)d_in[4];
    const float* beta1 = (const float*)d_in[5];
    const float* g2    = (const float*)d_in[6];
    const float* beta2 = (const float*)d_in[7];
    const float* Wff1  = (const float*)d_in[8];
    const float* bff1  = (const float*)d_in[9];
    const float* Wff2  = (const float*)d_in[10];
    const float* bff2  = (const float*)d_in[11];

    char* ws = (char*)d_ws;
    size_t off = 0;
    auto alloc = [&](size_t bytes) {
        void* p = ws + off;
        off += (bytes + 255) & ~(size_t)255;
        return p;
    };
    __hip_bfloat16* Wqkv_t = (__hip_bfloat16*)alloc(3072ULL * 1024 * 2);
    __hip_bfloat16* Wo_t   = (__hip_bfloat16*)alloc(1024ULL * 1024 * 2);
    __hip_bfloat16* Wff1_t = (__hip_bfloat16*)alloc(4096ULL * 1024 * 2);
    __hip_bfloat16* Wff2_t = (__hip_bfloat16*)alloc(1024ULL * 4096 * 2);
    __hip_bfloat16* h_bf   = (__hip_bfloat16*)alloc(4096ULL * 1024 * 2);
    __hip_bfloat16* qkv_bf = (__hip_bfloat16*)alloc(4096ULL * 3072 * 2);
    __hip_bfloat16* att_bf = (__hip_bfloat16*)alloc(4096ULL * 1024 * 2);
    float*          x2     = (float*)alloc(4096ULL * 1024 * 4);
    __hip_bfloat16* ff1_bf = qkv_bf;              // dead by FF time
    __hip_bfloat16* vt     = (__hip_bfloat16*)x2; // dead before Wo-gemm writes x2

    const dim3 tb(32, 8);
    tconv_k<<<dim3(3072 / 32, 1024 / 32), tb, 0, stream>>>(Wqkv, Wqkv_t, 1024, 3072);
    tconv_k<<<dim3(1024 / 32, 1024 / 32), tb, 0, stream>>>(Wo,   Wo_t,   1024, 1024);
    tconv_k<<<dim3(4096 / 32, 1024 / 32), tb, 0, stream>>>(Wff1, Wff1_t, 1024, 4096);
    tconv_k<<<dim3(1024 / 32, 4096 / 32), tb, 0, stream>>>(Wff2, Wff2_t, 4096, 1024);

    ln_k<<<4096, 256, 0, stream>>>(x, g1, beta1, h_bf);
    gemm_k<0, 0, 0, 1><<<dim3(3072 / 128, 4096 / 128), 256, 0, stream>>>(
        h_bf, Wqkv_t, nullptr, nullptr, qkv_bf, 4096, 3072, 1024);
    vtrans_k<<<dim3(32, 32), dim3(64, 4), 0, stream>>>(qkv_bf, vt);
    attn_k<<<dim3(32, 32), 256, 0, stream>>>(qkv_bf, vt, att_bf);
    gemm64_k<1, 0, 1, 0><<<dim3(1024 / 64, 4096 / 128), 256, 0, stream>>>(
        att_bf, Wo_t, b_o, x, x2, 4096, 1024, 1024);
    ln_k<<<4096, 256, 0, stream>>>(x2, g2, beta2, h_bf);
    gemm_k<1, 1, 0, 1><<<dim3(4096 / 128, 4096 / 128), 256, 0, stream>>>(
        h_bf, Wff1_t, bff1, nullptr, ff1_bf, 4096, 4096, 1024);
    gemm64_k<1, 0, 1, 0><<<dim3(1024 / 64, 4096 / 128), 256, 0, stream>>>(
        ff1_bf, Wff2_t, bff2, x2, (float*)d_out, 4096, 1024, 4096);
}

// Round 6
// 346.108 us; speedup vs baseline: 1.5735x; 1.1103x over previous
//
#include <hip/hip_runtime.h>
#include <hip/hip_bf16.h>
#include <stdint.h>

// ---------------------------------------------------------------------------
// TransformerDecoderBlock on MI355X (gfx950).  B=2, T=2048, C=1024, H=16, hd=64.
// R5: BK=64 GEMMs (half the barrier drains); attention staged via
//     global_load_lds into a double LDS buffer, ONE barrier/iter, full-iter
//     prefetch distance.  8-chunk XOR source-swizzle for all LDS tiles.
// ---------------------------------------------------------------------------

typedef __attribute__((ext_vector_type(8))) short bf16x8;   // 8 bf16 in 4 VGPRs
typedef __attribute__((ext_vector_type(4))) float f32x4;

#define MFMA16(a, b, c) __builtin_amdgcn_mfma_f32_16x16x32_bf16((a), (b), (c), 0, 0, 0)

__device__ __forceinline__ void gload16(const void* g, void* l) {
    __builtin_amdgcn_global_load_lds(
        (const __attribute__((address_space(1))) char*)g,
        (__attribute__((address_space(3))) char*)l, 16, 0, 0);
}

// --------------------------- transpose + fp32->bf16 ------------------------
__global__ __launch_bounds__(256) void tconv_k(const float* __restrict__ in,
                                               __hip_bfloat16* __restrict__ out,
                                               int K, int N) {
    __shared__ float tile[32][33];
    const int n0 = blockIdx.x * 32, k0 = blockIdx.y * 32;
    const int tx = threadIdx.x, ty = threadIdx.y;   // block (32, 8)
    for (int i = ty; i < 32; i += 8)
        tile[i][tx] = in[(size_t)(k0 + i) * N + n0 + tx];
    __syncthreads();
    for (int i = ty; i < 32; i += 8)
        out[(size_t)(n0 + i) * K + k0 + tx] = __float2bfloat16(tile[tx][i]);
}

// --------------------------------- layernorm -------------------------------
__global__ __launch_bounds__(256) void ln_k(const float* __restrict__ x,
                                            const float* __restrict__ g,
                                            const float* __restrict__ beta,
                                            __hip_bfloat16* __restrict__ out) {
    const int row = blockIdx.x;
    const int tid = threadIdx.x;
    float4 v = ((const float4*)(x + (size_t)row * 1024))[tid];
    float s  = v.x + v.y + v.z + v.w;
    float s2 = v.x * v.x + v.y * v.y + v.z * v.z + v.w * v.w;
    for (int off = 1; off < 64; off <<= 1) {
        s  += __shfl_xor(s,  off, 64);
        s2 += __shfl_xor(s2, off, 64);
    }
    __shared__ float ss[4], ss2[4];
    const int w = tid >> 6, lane = tid & 63;
    if (lane == 0) { ss[w] = s; ss2[w] = s2; }
    __syncthreads();
    s  = ss[0] + ss[1] + ss[2] + ss[3];
    s2 = ss2[0] + ss2[1] + ss2[2] + ss2[3];
    const float mu  = s * (1.0f / 1024.0f);
    const float var = s2 * (1.0f / 1024.0f) - mu * mu;
    const float rs  = rsqrtf(var + 1e-5f);
    float4 gv = ((const float4*)g)[tid];
    float4 bv = ((const float4*)beta)[tid];
    __hip_bfloat16* o = out + (size_t)row * 1024 + tid * 4;
    o[0] = __float2bfloat16((v.x - mu) * rs * gv.x + bv.x);
    o[1] = __float2bfloat16((v.y - mu) * rs * gv.y + bv.y);
    o[2] = __float2bfloat16((v.z - mu) * rs * gv.z + bv.z);
    o[3] = __float2bfloat16((v.w - mu) * rs * gv.w + bv.w);
}

// ------------------------- GEMM, BM=128 BN=128 BK=64 ------------------------
// Rows of 64 elems = 8 chunks of 16B.  Chunk (r,c) -> slot r*8 + ((c+(r&7))&7).
// Staging via global_load_lds: lane l of issue i covers slot i*256+w*64+l,
// i.e. row i*32+w*8+(l>>3), source chunk ((l&7)-(l>>3))&7 (source-swizzled).
template <int BIAS, int RELU, int RESID, int OUTBF>
__global__ __launch_bounds__(256, 3) void gemm_k(const __hip_bfloat16* __restrict__ A,
                                                 const __hip_bfloat16* __restrict__ Bt,
                                                 const float* __restrict__ bias,
                                                 const float* __restrict__ resid,
                                                 void* __restrict__ out,
                                                 int M, int N, int K) {
    __align__(16) __shared__ __hip_bfloat16 As[128 * 64];
    __align__(16) __shared__ __hip_bfloat16 Bs[128 * 64];

    const int tid  = threadIdx.x;
    const int lane = tid & 63, w = tid >> 6;
    const int wm = w >> 1, wn = w & 1;
    const int m0 = blockIdx.y * 128, n0 = blockIdx.x * 128;
    const int l16 = lane & 15, quad = lane >> 4;

    const int srw = lane >> 3;                 // 0..7
    const int scn = ((lane & 7) - srw) & 7;    // source chunk (swizzled)

    const __hip_bfloat16* ga[4];
    const __hip_bfloat16* gb[4];
#pragma unroll
    for (int i = 0; i < 4; i++) {
        const int row = i * 32 + w * 8 + srw;
        ga[i] = A  + (size_t)(m0 + row) * K + scn * 8;
        gb[i] = Bt + (size_t)(n0 + row) * K + scn * 8;
    }

    int offA[2][4], offB[2][4];
#pragma unroll
    for (int s = 0; s < 2; s++)
#pragma unroll
        for (int t = 0; t < 4; t++) {
            const int rA = wm * 64 + t * 16 + l16;
            offA[s][t] = (rA * 8 + ((s * 4 + quad + (rA & 7)) & 7)) * 16;
            const int rB = wn * 64 + t * 16 + l16;
            offB[s][t] = (rB * 8 + ((s * 4 + quad + (rB & 7)) & 7)) * 16;
        }

    f32x4 acc[4][4] = {};

    for (int k0 = 0; k0 < K; k0 += 64) {
        __syncthreads();
#pragma unroll
        for (int i = 0; i < 4; i++) {
            gload16(ga[i], As + (i * 256 + w * 64) * 8);
            gload16(gb[i], Bs + (i * 256 + w * 64) * 8);
            ga[i] += 64; gb[i] += 64;
        }
        __syncthreads();

#pragma unroll
        for (int s = 0; s < 2; s++) {
            bf16x8 af[4], bfr[4];
#pragma unroll
            for (int t = 0; t < 4; t++) {
                af[t]  = *(const bf16x8*)((const char*)As + offA[s][t]);
                bfr[t] = *(const bf16x8*)((const char*)Bs + offB[s][t]);
            }
#pragma unroll
            for (int mt = 0; mt < 4; mt++)
#pragma unroll
                for (int nt = 0; nt < 4; nt++)
                    acc[mt][nt] = MFMA16(af[mt], bfr[nt], acc[mt][nt]);
        }
    }

#pragma unroll
    for (int mt = 0; mt < 4; mt++)
#pragma unroll
        for (int nt = 0; nt < 4; nt++) {
            const int row = m0 + wm * 64 + mt * 16 + quad * 4;
            const int col = n0 + wn * 64 + nt * 16 + l16;
            const float bv = BIAS ? bias[col] : 0.0f;
#pragma unroll
            for (int r = 0; r < 4; r++) {
                float v = acc[mt][nt][r] + bv;
                if (RELU) v = v > 0.0f ? v : 0.0f;
                const size_t idx = (size_t)(row + r) * N + col;
                if (RESID) v += resid[idx];
                if (OUTBF) ((__hip_bfloat16*)out)[idx] = __float2bfloat16(v);
                else       ((float*)out)[idx] = v;
            }
        }
}

// ------------------------- GEMM, BM=128 BN=64 BK=64 -------------------------
template <int BIAS, int RELU, int RESID, int OUTBF>
__global__ __launch_bounds__(256, 3) void gemm64_k(const __hip_bfloat16* __restrict__ A,
                                                   const __hip_bfloat16* __restrict__ Bt,
                                                   const float* __restrict__ bias,
                                                   const float* __restrict__ resid,
                                                   void* __restrict__ out,
                                                   int M, int N, int K) {
    __align__(16) __shared__ __hip_bfloat16 As[128 * 64];
    __align__(16) __shared__ __hip_bfloat16 Bs[64 * 64];

    const int tid  = threadIdx.x;
    const int lane = tid & 63, w = tid >> 6;
    const int wm = w >> 1, wn = w & 1;
    const int m0 = blockIdx.y * 128, n0 = blockIdx.x * 64;
    const int l16 = lane & 15, quad = lane >> 4;

    const int srw = lane >> 3;
    const int scn = ((lane & 7) - srw) & 7;

    const __hip_bfloat16* ga[4];
    const __hip_bfloat16* gb[2];
#pragma unroll
    for (int i = 0; i < 4; i++)
        ga[i] = A + (size_t)(m0 + i * 32 + w * 8 + srw) * K + scn * 8;
#pragma unroll
    for (int i = 0; i < 2; i++)
        gb[i] = Bt + (size_t)(n0 + i * 32 + w * 8 + srw) * K + scn * 8;

    int offA[2][4], offB[2][2];
#pragma unroll
    for (int s = 0; s < 2; s++) {
#pragma unroll
        for (int t = 0; t < 4; t++) {
            const int rA = wm * 64 + t * 16 + l16;
            offA[s][t] = (rA * 8 + ((s * 4 + quad + (rA & 7)) & 7)) * 16;
        }
#pragma unroll
        for (int t = 0; t < 2; t++) {
            const int rB = wn * 32 + t * 16 + l16;
            offB[s][t] = (rB * 8 + ((s * 4 + quad + (rB & 7)) & 7)) * 16;
        }
    }

    f32x4 acc[4][2] = {};

    for (int k0 = 0; k0 < K; k0 += 64) {
        __syncthreads();
#pragma unroll
        for (int i = 0; i < 4; i++) {
            gload16(ga[i], As + (i * 256 + w * 64) * 8);
            ga[i] += 64;
        }
#pragma unroll
        for (int i = 0; i < 2; i++) {
            gload16(gb[i], Bs + (i * 256 + w * 64) * 8);
            gb[i] += 64;
        }
        __syncthreads();

#pragma unroll
        for (int s = 0; s < 2; s++) {
            bf16x8 af[4], bfr[2];
#pragma unroll
            for (int t = 0; t < 4; t++)
                af[t] = *(const bf16x8*)((const char*)As + offA[s][t]);
#pragma unroll
            for (int t = 0; t < 2; t++)
                bfr[t] = *(const bf16x8*)((const char*)Bs + offB[s][t]);
#pragma unroll
            for (int mt = 0; mt < 4; mt++)
#pragma unroll
                for (int nt = 0; nt < 2; nt++)
                    acc[mt][nt] = MFMA16(af[mt], bfr[nt], acc[mt][nt]);
        }
    }

#pragma unroll
    for (int mt = 0; mt < 4; mt++)
#pragma unroll
        for (int nt = 0; nt < 2; nt++) {
            const int row = m0 + wm * 64 + mt * 16 + quad * 4;
            const int col = n0 + wn * 32 + nt * 16 + l16;
            const float bv = BIAS ? bias[col] : 0.0f;
#pragma unroll
            for (int r = 0; r < 4; r++) {
                float v = acc[mt][nt][r] + bv;
                if (RELU) v = v > 0.0f ? v : 0.0f;
                const size_t idx = (size_t)(row + r) * N + col;
                if (RESID) v += resid[idx];
                if (OUTBF) ((__hip_bfloat16*)out)[idx] = __float2bfloat16(v);
                else       ((float*)out)[idx] = v;
            }
        }
}

// ----------------------- V transpose: qkv -> Vt[bh][d][T] -------------------
__global__ __launch_bounds__(256) void vtrans_k(const __hip_bfloat16* __restrict__ qkv,
                                                __hip_bfloat16* __restrict__ vt) {
    const int T = 2048, C3 = 3072;
    const int bh = blockIdx.y, b = bh >> 4, h = bh & 15;
    const int t0 = blockIdx.x * 64;
    const int tx = threadIdx.x, ty = threadIdx.y;   // block (64, 4)
    __shared__ __hip_bfloat16 tile[64][65];
#pragma unroll
    for (int j = 0; j < 16; j++) {
        const int tl = ty * 16 + j;
        tile[tl][tx] = qkv[(size_t)(b * T + t0 + tl) * C3 + 2048 + h * 64 + tx];
    }
    __syncthreads();
#pragma unroll
    for (int j = 0; j < 16; j++) {
        const int d = ty * 16 + j;
        vt[((size_t)bh * 64 + d) * 2048 + t0 + tx] = tile[tx][d];
    }
}

// ------------------------------ flash attention -----------------------------
// Fixed-max softmax; 64 q-rows/block, 4 waves x 16 rows.  K/V staged via
// global_load_lds (source-swizzled) into double LDS buffers; ONE barrier/iter,
// prefetch issued right after the barrier -> full-iteration latency hiding.
__global__ __launch_bounds__(256, 3) void attn_k(const __hip_bfloat16* __restrict__ qkv,
                                                 const __hip_bfloat16* __restrict__ vt,
                                                 __hip_bfloat16* __restrict__ outp) {
    const int T = 2048, C3 = 3072;
    const int bh = blockIdx.x, b = bh >> 4, h = bh & 15;
    const int qt = 31 - blockIdx.y;           // heavy q-tiles dispatched first
    const int q0 = qt * 64;
    const int tid = threadIdx.x, lane = tid & 63, w = tid >> 6;
    const int l16 = lane & 15, quad = lane >> 4;

    __align__(16) __shared__ __hip_bfloat16 Ks[2][64 * 64];   // swizzled [key][d]
    __align__(16) __shared__ __hip_bfloat16 Vs[2][64 * 64];   // swizzled [d][key]
    __align__(16) __shared__ __hip_bfloat16 Pw[4][16 * 72];   // per-wave P

    // Q fragments, pre-scaled by log2e/8 (exp2 domain)
    const float sc = 0.125f * 1.44269504f;
    bf16x8 qf0, qf1;
    {
        const __hip_bfloat16* qp =
            qkv + (size_t)(b * T + q0 + w * 16 + l16) * C3 + h * 64;
        bf16x8 a = *(const bf16x8*)(qp + quad * 8);
        bf16x8 c = *(const bf16x8*)(qp + 32 + quad * 8);
#pragma unroll
        for (int i = 0; i < 8; i++) {
            union { unsigned int u; float f; } ua, uc;
            ua.u = ((unsigned int)(unsigned short)a[i]) << 16;
            uc.u = ((unsigned int)(unsigned short)c[i]) << 16;
            qf0[i] = (short)(__bfloat16_as_ushort(__float2bfloat16(ua.f * sc)));
            qf1[i] = (short)(__bfloat16_as_ushort(__float2bfloat16(uc.f * sc)));
        }
    }

    // staging source pointers (swizzled chunk per lane)
    const int srw = lane >> 3;
    const int scn = ((lane & 7) - srw) & 7;
    const __hip_bfloat16* kp[2];
    const __hip_bfloat16* vp[2];
#pragma unroll
    for (int i = 0; i < 2; i++) {
        const int row = i * 32 + w * 8 + srw;
        kp[i] = qkv + (size_t)(b * T + row) * C3 + 1024 + h * 64 + scn * 8;
        vp[i] = vt + ((size_t)bh * 64 + row) * 2048 + scn * 8;
    }

    // fragment LDS byte offsets
    int offK[2][4], offV[2][4];
#pragma unroll
    for (int s = 0; s < 2; s++)
#pragma unroll
        for (int t = 0; t < 4; t++) {
            const int rr = t * 16 + l16;
            const int o = (rr * 8 + ((s * 4 + quad + (rr & 7)) & 7)) * 16;
            offK[s][t] = o;
            offV[s][t] = o;
        }

    f32x4 oacc[4] = {};
    float lpart[4] = {0.0f, 0.0f, 0.0f, 0.0f};

    // prologue: stage tile 0 into buf 0
#pragma unroll
    for (int i = 0; i < 2; i++) {
        gload16(kp[i], Ks[0] + (i * 256 + w * 64) * 8);
        gload16(vp[i], Vs[0] + (i * 256 + w * 64) * 8);
    }

    for (int kt = 0; kt <= qt; kt++) {
        const int buf = kt & 1;
        __syncthreads();   // drains vmcnt -> buf ready; prev reads of buf^1 done
        if (kt < qt) {
#pragma unroll
            for (int i = 0; i < 2; i++) {
                gload16(kp[i] + (size_t)(kt + 1) * 64 * C3,
                        Ks[buf ^ 1] + (i * 256 + w * 64) * 8);
                gload16(vp[i] + (kt + 1) * 64,
                        Vs[buf ^ 1] + (i * 256 + w * 64) * 8);
            }
        }

        // ---- S = (Q*sc) K^T ----
        f32x4 s4[4];
#pragma unroll
        for (int nt = 0; nt < 4; nt++) {
            bf16x8 kf0 = *(const bf16x8*)((const char*)Ks[buf] + offK[0][nt]);
            bf16x8 kf1 = *(const bf16x8*)((const char*)Ks[buf] + offK[1][nt]);
            f32x4 z = {};
            z = MFMA16(qf0, kf0, z);
            z = MFMA16(qf1, kf1, z);
            s4[nt] = z;
        }

        // ---- p = exp2(s) (+ diagonal mask), accumulate l, write P ----
        const bool diag = (kt == qt);
        const int myrow = w * 16 + quad * 4;      // q-row within 64-row tile
#pragma unroll
        for (int nt = 0; nt < 4; nt++) {
            const int col = nt * 16 + l16;
#pragma unroll
            for (int r = 0; r < 4; r++) {
                float p = exp2f(s4[nt][r]);
                if (diag && col > myrow + r) p = 0.0f;
                lpart[r] += p;
                Pw[w][(quad * 4 + r) * 72 + col] = __float2bfloat16(p);
            }
        }

        asm volatile("s_waitcnt lgkmcnt(0)" ::: "memory");  // own-wave P visible

        // ---- O += P @ V ----
        bf16x8 pf0 = *(const bf16x8*)(&Pw[w][l16 * 72 + quad * 8]);
        bf16x8 pf1 = *(const bf16x8*)(&Pw[w][l16 * 72 + 32 + quad * 8]);
#pragma unroll
        for (int dt = 0; dt < 4; dt++) {
            bf16x8 vf0 = *(const bf16x8*)((const char*)Vs[buf] + offV[0][dt]);
            bf16x8 vf1 = *(const bf16x8*)((const char*)Vs[buf] + offV[1][dt]);
            oacc[dt] = MFMA16(pf0, vf0, oacc[dt]);
            oacc[dt] = MFMA16(pf1, vf1, oacc[dt]);
        }
    }

    // deferred l-reduction across the 16 lanes sharing a quad-row
#pragma unroll
    for (int off = 1; off < 16; off <<= 1)
#pragma unroll
        for (int r = 0; r < 4; r++)
            lpart[r] += __shfl_xor(lpart[r], off, 64);

    float rl[4];
#pragma unroll
    for (int r = 0; r < 4; r++) rl[r] = 1.0f / lpart[r];
#pragma unroll
    for (int dt = 0; dt < 4; dt++)
#pragma unroll
        for (int r = 0; r < 4; r++) {
            const int row = q0 + w * 16 + quad * 4 + r;
            outp[(size_t)(b * T + row) * 1024 + h * 64 + dt * 16 + l16] =
                __float2bfloat16(oacc[dt][r] * rl[r]);
        }
}

// --------------------------------- launcher --------------------------------
extern "C" void kernel_launch(void* const* d_in, const int* in_sizes, int n_in,
                              void* d_out, int out_size, void* d_ws, size_t ws_size,
                              hipStream_t stream) {
    const float* x     = (const float*)d_in[0];
    const float* Wqkv  = (const float*)d_in[1];
    const float* Wo    = (const float*)d_in[2];
    const float* b_o   = (const float*)d_in[3];
    const float* g1    = (const float*)d_in[4];
    const float* beta1 = (const float*)d_in[5];
    const float* g2    = (const float*)d_in[6];
    const float* beta2 = (const float*)d_in[7];
    const float* Wff1  = (const float*)d_in[8];
    const float* bff1  = (const float*)d_in[9];
    const float* Wff2  = (const float*)d_in[10];
    const float* bff2  = (const float*)d_in[11];

    char* ws = (char*)d_ws;
    size_t off = 0;
    auto alloc = [&](size_t bytes) {
        void* p = ws + off;
        off += (bytes + 255) & ~(size_t)255;
        return p;
    };
    __hip_bfloat16* Wqkv_t = (__hip_bfloat16*)alloc(3072ULL * 1024 * 2);
    __hip_bfloat16* Wo_t   = (__hip_bfloat16*)alloc(1024ULL * 1024 * 2);
    __hip_bfloat16* Wff1_t = (__hip_bfloat16*)alloc(4096ULL * 1024 * 2);
    __hip_bfloat16* Wff2_t = (__hip_bfloat16*)alloc(1024ULL * 4096 * 2);
    __hip_bfloat16* h_bf   = (__hip_bfloat16*)alloc(4096ULL * 1024 * 2);
    __hip_bfloat16* qkv_bf = (__hip_bfloat16*)alloc(4096ULL * 3072 * 2);
    __hip_bfloat16* att_bf = (__hip_bfloat16*)alloc(4096ULL * 1024 * 2);
    float*          x2     = (float*)alloc(4096ULL * 1024 * 4);
    __hip_bfloat16* ff1_bf = qkv_bf;              // dead by FF time
    __hip_bfloat16* vt     = (__hip_bfloat16*)x2; // dead before Wo-gemm writes x2

    const dim3 tb(32, 8);
    tconv_k<<<dim3(3072 / 32, 1024 / 32), tb, 0, stream>>>(Wqkv, Wqkv_t, 1024, 3072);
    tconv_k<<<dim3(1024 / 32, 1024 / 32), tb, 0, stream>>>(Wo,   Wo_t,   1024, 1024);
    tconv_k<<<dim3(4096 / 32, 1024 / 32), tb, 0, stream>>>(Wff1, Wff1_t, 1024, 4096);
    tconv_k<<<dim3(1024 / 32, 4096 / 32), tb, 0, stream>>>(Wff2, Wff2_t, 4096, 1024);

    ln_k<<<4096, 256, 0, stream>>>(x, g1, beta1, h_bf);
    gemm_k<0, 0, 0, 1><<<dim3(3072 / 128, 4096 / 128), 256, 0, stream>>>(
        h_bf, Wqkv_t, nullptr, nullptr, qkv_bf, 4096, 3072, 1024);
    vtrans_k<<<dim3(32, 32), dim3(64, 4), 0, stream>>>(qkv_bf, vt);
    attn_k<<<dim3(32, 32), 256, 0, stream>>>(qkv_bf, vt, att_bf);
    gemm64_k<1, 0, 1, 0><<<dim3(1024 / 64, 4096 / 128), 256, 0, stream>>>(
        att_bf, Wo_t, b_o, x, x2, 4096, 1024, 1024);
    ln_k<<<4096, 256, 0, stream>>>(x2, g2, beta2, h_bf);
    gemm_k<1, 1, 0, 1><<<dim3(4096 / 128, 4096 / 128), 256, 0, stream>>>(
        h_bf, Wff1_t, bff1, nullptr, ff1_bf, 4096, 4096, 1024);
    gemm64_k<1, 0, 1, 0><<<dim3(1024 / 64, 4096 / 128), 256, 0, stream>>>(
        ff1_bf, Wff2_t, bff2, x2, (float*)d_out, 4096, 1024, 4096);
}

// Round 7
// 340.620 us; speedup vs baseline: 1.5988x; 1.0161x over previous
//
#include <hip/hip_runtime.h>
#include <hip/hip_bf16.h>
#include <stdint.h>

// ---------------------------------------------------------------------------
// TransformerDecoderBlock on MI355X (gfx950).  B=2, T=2048, C=1024, H=16, hd=64.
// R6: single-barrier double-buffered GEMMs (prefetch tile k+1 into buf^1 right
//     after the barrier -> full-iteration prefetch distance), same structure
//     that fixed attention in R5.  BK=64, XOR source-swizzle, 0 bank conflicts.
// ---------------------------------------------------------------------------

typedef __attribute__((ext_vector_type(8))) short bf16x8;   // 8 bf16 in 4 VGPRs
typedef __attribute__((ext_vector_type(4))) float f32x4;

#define MFMA16(a, b, c) __builtin_amdgcn_mfma_f32_16x16x32_bf16((a), (b), (c), 0, 0, 0)

__device__ __forceinline__ void gload16(const void* g, void* l) {
    __builtin_amdgcn_global_load_lds(
        (const __attribute__((address_space(1))) char*)g,
        (__attribute__((address_space(3))) char*)l, 16, 0, 0);
}

// --------------------------- transpose + fp32->bf16 ------------------------
__global__ __launch_bounds__(256) void tconv_k(const float* __restrict__ in,
                                               __hip_bfloat16* __restrict__ out,
                                               int K, int N) {
    __shared__ float tile[32][33];
    const int n0 = blockIdx.x * 32, k0 = blockIdx.y * 32;
    const int tx = threadIdx.x, ty = threadIdx.y;   // block (32, 8)
    for (int i = ty; i < 32; i += 8)
        tile[i][tx] = in[(size_t)(k0 + i) * N + n0 + tx];
    __syncthreads();
    for (int i = ty; i < 32; i += 8)
        out[(size_t)(n0 + i) * K + k0 + tx] = __float2bfloat16(tile[tx][i]);
}

// --------------------------------- layernorm -------------------------------
__global__ __launch_bounds__(256) void ln_k(const float* __restrict__ x,
                                            const float* __restrict__ g,
                                            const float* __restrict__ beta,
                                            __hip_bfloat16* __restrict__ out) {
    const int row = blockIdx.x;
    const int tid = threadIdx.x;
    float4 v = ((const float4*)(x + (size_t)row * 1024))[tid];
    float s  = v.x + v.y + v.z + v.w;
    float s2 = v.x * v.x + v.y * v.y + v.z * v.z + v.w * v.w;
    for (int off = 1; off < 64; off <<= 1) {
        s  += __shfl_xor(s,  off, 64);
        s2 += __shfl_xor(s2, off, 64);
    }
    __shared__ float ss[4], ss2[4];
    const int w = tid >> 6, lane = tid & 63;
    if (lane == 0) { ss[w] = s; ss2[w] = s2; }
    __syncthreads();
    s  = ss[0] + ss[1] + ss[2] + ss[3];
    s2 = ss2[0] + ss2[1] + ss2[2] + ss2[3];
    const float mu  = s * (1.0f / 1024.0f);
    const float var = s2 * (1.0f / 1024.0f) - mu * mu;
    const float rs  = rsqrtf(var + 1e-5f);
    float4 gv = ((const float4*)g)[tid];
    float4 bv = ((const float4*)beta)[tid];
    __hip_bfloat16* o = out + (size_t)row * 1024 + tid * 4;
    o[0] = __float2bfloat16((v.x - mu) * rs * gv.x + bv.x);
    o[1] = __float2bfloat16((v.y - mu) * rs * gv.y + bv.y);
    o[2] = __float2bfloat16((v.z - mu) * rs * gv.z + bv.z);
    o[3] = __float2bfloat16((v.w - mu) * rs * gv.w + bv.w);
}

// ------------------- GEMM, BM=128 BN=128 BK=64, dbuf 1-barrier ---------------
// Rows of 64 elems = 8 chunks of 16B.  Chunk (r,c) -> slot r*8 + ((c+(r&7))&7).
template <int BIAS, int RELU, int RESID, int OUTBF>
__global__ __launch_bounds__(256, 2) void gemm_k(const __hip_bfloat16* __restrict__ A,
                                                 const __hip_bfloat16* __restrict__ Bt,
                                                 const float* __restrict__ bias,
                                                 const float* __restrict__ resid,
                                                 void* __restrict__ out,
                                                 int M, int N, int K) {
    __align__(16) __shared__ __hip_bfloat16 As[2][128 * 64];
    __align__(16) __shared__ __hip_bfloat16 Bs[2][128 * 64];

    const int tid  = threadIdx.x;
    const int lane = tid & 63, w = tid >> 6;
    const int wm = w >> 1, wn = w & 1;
    const int m0 = blockIdx.y * 128, n0 = blockIdx.x * 128;
    const int l16 = lane & 15, quad = lane >> 4;

    const int srw = lane >> 3;                 // 0..7
    const int scn = ((lane & 7) - srw) & 7;    // source chunk (swizzled)

    const __hip_bfloat16* ga[4];
    const __hip_bfloat16* gb[4];
#pragma unroll
    for (int i = 0; i < 4; i++) {
        const int row = i * 32 + w * 8 + srw;
        ga[i] = A  + (size_t)(m0 + row) * K + scn * 8;
        gb[i] = Bt + (size_t)(n0 + row) * K + scn * 8;
    }

    int offA[2][4], offB[2][4];
#pragma unroll
    for (int s = 0; s < 2; s++)
#pragma unroll
        for (int t = 0; t < 4; t++) {
            const int rA = wm * 64 + t * 16 + l16;
            offA[s][t] = (rA * 8 + ((s * 4 + quad + (rA & 7)) & 7)) * 16;
            const int rB = wn * 64 + t * 16 + l16;
            offB[s][t] = (rB * 8 + ((s * 4 + quad + (rB & 7)) & 7)) * 16;
        }

    f32x4 acc[4][4] = {};

    // prologue: stage tile 0 into buf 0
#pragma unroll
    for (int i = 0; i < 4; i++) {
        gload16(ga[i], As[0] + (i * 256 + w * 64) * 8);
        gload16(gb[i], Bs[0] + (i * 256 + w * 64) * 8);
        ga[i] += 64; gb[i] += 64;
    }

    const int niter = K >> 6;
    for (int it = 0; it < niter; it++) {
        const int buf = it & 1;
        __syncthreads();   // drains prefetch into buf (issued prev iter)
        if (it + 1 < niter) {
#pragma unroll
            for (int i = 0; i < 4; i++) {
                gload16(ga[i], As[buf ^ 1] + (i * 256 + w * 64) * 8);
                gload16(gb[i], Bs[buf ^ 1] + (i * 256 + w * 64) * 8);
                ga[i] += 64; gb[i] += 64;
            }
        }

#pragma unroll
        for (int s = 0; s < 2; s++) {
            bf16x8 af[4], bfr[4];
#pragma unroll
            for (int t = 0; t < 4; t++) {
                af[t]  = *(const bf16x8*)((const char*)As[buf] + offA[s][t]);
                bfr[t] = *(const bf16x8*)((const char*)Bs[buf] + offB[s][t]);
            }
#pragma unroll
            for (int mt = 0; mt < 4; mt++)
#pragma unroll
                for (int nt = 0; nt < 4; nt++)
                    acc[mt][nt] = MFMA16(af[mt], bfr[nt], acc[mt][nt]);
        }
    }

#pragma unroll
    for (int mt = 0; mt < 4; mt++)
#pragma unroll
        for (int nt = 0; nt < 4; nt++) {
            const int row = m0 + wm * 64 + mt * 16 + quad * 4;
            const int col = n0 + wn * 64 + nt * 16 + l16;
            const float bv = BIAS ? bias[col] : 0.0f;
#pragma unroll
            for (int r = 0; r < 4; r++) {
                float v = acc[mt][nt][r] + bv;
                if (RELU) v = v > 0.0f ? v : 0.0f;
                const size_t idx = (size_t)(row + r) * N + col;
                if (RESID) v += resid[idx];
                if (OUTBF) ((__hip_bfloat16*)out)[idx] = __float2bfloat16(v);
                else       ((float*)out)[idx] = v;
            }
        }
}

// ------------------- GEMM, BM=128 BN=64 BK=64, dbuf 1-barrier ----------------
template <int BIAS, int RELU, int RESID, int OUTBF>
__global__ __launch_bounds__(256, 3) void gemm64_k(const __hip_bfloat16* __restrict__ A,
                                                   const __hip_bfloat16* __restrict__ Bt,
                                                   const float* __restrict__ bias,
                                                   const float* __restrict__ resid,
                                                   void* __restrict__ out,
                                                   int M, int N, int K) {
    __align__(16) __shared__ __hip_bfloat16 As[2][128 * 64];
    __align__(16) __shared__ __hip_bfloat16 Bs[2][64 * 64];

    const int tid  = threadIdx.x;
    const int lane = tid & 63, w = tid >> 6;
    const int wm = w >> 1, wn = w & 1;
    const int m0 = blockIdx.y * 128, n0 = blockIdx.x * 64;
    const int l16 = lane & 15, quad = lane >> 4;

    const int srw = lane >> 3;
    const int scn = ((lane & 7) - srw) & 7;

    const __hip_bfloat16* ga[4];
    const __hip_bfloat16* gb[2];
#pragma unroll
    for (int i = 0; i < 4; i++)
        ga[i] = A + (size_t)(m0 + i * 32 + w * 8 + srw) * K + scn * 8;
#pragma unroll
    for (int i = 0; i < 2; i++)
        gb[i] = Bt + (size_t)(n0 + i * 32 + w * 8 + srw) * K + scn * 8;

    int offA[2][4], offB[2][2];
#pragma unroll
    for (int s = 0; s < 2; s++) {
#pragma unroll
        for (int t = 0; t < 4; t++) {
            const int rA = wm * 64 + t * 16 + l16;
            offA[s][t] = (rA * 8 + ((s * 4 + quad + (rA & 7)) & 7)) * 16;
        }
#pragma unroll
        for (int t = 0; t < 2; t++) {
            const int rB = wn * 32 + t * 16 + l16;
            offB[s][t] = (rB * 8 + ((s * 4 + quad + (rB & 7)) & 7)) * 16;
        }
    }

    f32x4 acc[4][2] = {};

    // prologue: stage tile 0 into buf 0
#pragma unroll
    for (int i = 0; i < 4; i++) {
        gload16(ga[i], As[0] + (i * 256 + w * 64) * 8);
        ga[i] += 64;
    }
#pragma unroll
    for (int i = 0; i < 2; i++) {
        gload16(gb[i], Bs[0] + (i * 256 + w * 64) * 8);
        gb[i] += 64;
    }

    const int niter = K >> 6;
    for (int it = 0; it < niter; it++) {
        const int buf = it & 1;
        __syncthreads();   // drains prefetch into buf
        if (it + 1 < niter) {
#pragma unroll
            for (int i = 0; i < 4; i++) {
                gload16(ga[i], As[buf ^ 1] + (i * 256 + w * 64) * 8);
                ga[i] += 64;
            }
#pragma unroll
            for (int i = 0; i < 2; i++) {
                gload16(gb[i], Bs[buf ^ 1] + (i * 256 + w * 64) * 8);
                gb[i] += 64;
            }
        }

#pragma unroll
        for (int s = 0; s < 2; s++) {
            bf16x8 af[4], bfr[2];
#pragma unroll
            for (int t = 0; t < 4; t++)
                af[t] = *(const bf16x8*)((const char*)As[buf] + offA[s][t]);
#pragma unroll
            for (int t = 0; t < 2; t++)
                bfr[t] = *(const bf16x8*)((const char*)Bs[buf] + offB[s][t]);
#pragma unroll
            for (int mt = 0; mt < 4; mt++)
#pragma unroll
                for (int nt = 0; nt < 2; nt++)
                    acc[mt][nt] = MFMA16(af[mt], bfr[nt], acc[mt][nt]);
        }
    }

#pragma unroll
    for (int mt = 0; mt < 4; mt++)
#pragma unroll
        for (int nt = 0; nt < 2; nt++) {
            const int row = m0 + wm * 64 + mt * 16 + quad * 4;
            const int col = n0 + wn * 32 + nt * 16 + l16;
            const float bv = BIAS ? bias[col] : 0.0f;
#pragma unroll
            for (int r = 0; r < 4; r++) {
                float v = acc[mt][nt][r] + bv;
                if (RELU) v = v > 0.0f ? v : 0.0f;
                const size_t idx = (size_t)(row + r) * N + col;
                if (RESID) v += resid[idx];
                if (OUTBF) ((__hip_bfloat16*)out)[idx] = __float2bfloat16(v);
                else       ((float*)out)[idx] = v;
            }
        }
}

// ----------------------- V transpose: qkv -> Vt[bh][d][T] -------------------
__global__ __launch_bounds__(256) void vtrans_k(const __hip_bfloat16* __restrict__ qkv,
                                                __hip_bfloat16* __restrict__ vt) {
    const int T = 2048, C3 = 3072;
    const int bh = blockIdx.y, b = bh >> 4, h = bh & 15;
    const int t0 = blockIdx.x * 64;
    const int tx = threadIdx.x, ty = threadIdx.y;   // block (64, 4)
    __shared__ __hip_bfloat16 tile[64][65];
#pragma unroll
    for (int j = 0; j < 16; j++) {
        const int tl = ty * 16 + j;
        tile[tl][tx] = qkv[(size_t)(b * T + t0 + tl) * C3 + 2048 + h * 64 + tx];
    }
    __syncthreads();
#pragma unroll
    for (int j = 0; j < 16; j++) {
        const int d = ty * 16 + j;
        vt[((size_t)bh * 64 + d) * 2048 + t0 + tx] = tile[tx][d];
    }
}

// ------------------------------ flash attention -----------------------------
// Fixed-max softmax; 64 q-rows/block, 4 waves x 16 rows.  K/V staged via
// global_load_lds (source-swizzled) into double LDS buffers; ONE barrier/iter.
__global__ __launch_bounds__(256, 3) void attn_k(const __hip_bfloat16* __restrict__ qkv,
                                                 const __hip_bfloat16* __restrict__ vt,
                                                 __hip_bfloat16* __restrict__ outp) {
    const int T = 2048, C3 = 3072;
    const int bh = blockIdx.x, b = bh >> 4, h = bh & 15;
    const int qt = 31 - blockIdx.y;           // heavy q-tiles dispatched first
    const int q0 = qt * 64;
    const int tid = threadIdx.x, lane = tid & 63, w = tid >> 6;
    const int l16 = lane & 15, quad = lane >> 4;

    __align__(16) __shared__ __hip_bfloat16 Ks[2][64 * 64];   // swizzled [key][d]
    __align__(16) __shared__ __hip_bfloat16 Vs[2][64 * 64];   // swizzled [d][key]
    __align__(16) __shared__ __hip_bfloat16 Pw[4][16 * 72];   // per-wave P

    const float sc = 0.125f * 1.44269504f;
    bf16x8 qf0, qf1;
    {
        const __hip_bfloat16* qp =
            qkv + (size_t)(b * T + q0 + w * 16 + l16) * C3 + h * 64;
        bf16x8 a = *(const bf16x8*)(qp + quad * 8);
        bf16x8 c = *(const bf16x8*)(qp + 32 + quad * 8);
#pragma unroll
        for (int i = 0; i < 8; i++) {
            union { unsigned int u; float f; } ua, uc;
            ua.u = ((unsigned int)(unsigned short)a[i]) << 16;
            uc.u = ((unsigned int)(unsigned short)c[i]) << 16;
            qf0[i] = (short)(__bfloat16_as_ushort(__float2bfloat16(ua.f * sc)));
            qf1[i] = (short)(__bfloat16_as_ushort(__float2bfloat16(uc.f * sc)));
        }
    }

    const int srw = lane >> 3;
    const int scn = ((lane & 7) - srw) & 7;
    const __hip_bfloat16* kp[2];
    const __hip_bfloat16* vp[2];
#pragma unroll
    for (int i = 0; i < 2; i++) {
        const int row = i * 32 + w * 8 + srw;
        kp[i] = qkv + (size_t)(b * T + row) * C3 + 1024 + h * 64 + scn * 8;
        vp[i] = vt + ((size_t)bh * 64 + row) * 2048 + scn * 8;
    }

    int offK[2][4];
#pragma unroll
    for (int s = 0; s < 2; s++)
#pragma unroll
        for (int t = 0; t < 4; t++) {
            const int rr = t * 16 + l16;
            offK[s][t] = (rr * 8 + ((s * 4 + quad + (rr & 7)) & 7)) * 16;
        }

    f32x4 oacc[4] = {};
    float lpart[4] = {0.0f, 0.0f, 0.0f, 0.0f};

#pragma unroll
    for (int i = 0; i < 2; i++) {
        gload16(kp[i], Ks[0] + (i * 256 + w * 64) * 8);
        gload16(vp[i], Vs[0] + (i * 256 + w * 64) * 8);
    }

    for (int kt = 0; kt <= qt; kt++) {
        const int buf = kt & 1;
        __syncthreads();
        if (kt < qt) {
#pragma unroll
            for (int i = 0; i < 2; i++) {
                gload16(kp[i] + (size_t)(kt + 1) * 64 * C3,
                        Ks[buf ^ 1] + (i * 256 + w * 64) * 8);
                gload16(vp[i] + (kt + 1) * 64,
                        Vs[buf ^ 1] + (i * 256 + w * 64) * 8);
            }
        }

        f32x4 s4[4];
#pragma unroll
        for (int nt = 0; nt < 4; nt++) {
            bf16x8 kf0 = *(const bf16x8*)((const char*)Ks[buf] + offK[0][nt]);
            bf16x8 kf1 = *(const bf16x8*)((const char*)Ks[buf] + offK[1][nt]);
            f32x4 z = {};
            z = MFMA16(qf0, kf0, z);
            z = MFMA16(qf1, kf1, z);
            s4[nt] = z;
        }

        const bool diag = (kt == qt);
        const int myrow = w * 16 + quad * 4;
#pragma unroll
        for (int nt = 0; nt < 4; nt++) {
            const int col = nt * 16 + l16;
#pragma unroll
            for (int r = 0; r < 4; r++) {
                float p = exp2f(s4[nt][r]);
                if (diag && col > myrow + r) p = 0.0f;
                lpart[r] += p;
                Pw[w][(quad * 4 + r) * 72 + col] = __float2bfloat16(p);
            }
        }

        asm volatile("s_waitcnt lgkmcnt(0)" ::: "memory");

        bf16x8 pf0 = *(const bf16x8*)(&Pw[w][l16 * 72 + quad * 8]);
        bf16x8 pf1 = *(const bf16x8*)(&Pw[w][l16 * 72 + 32 + quad * 8]);
#pragma unroll
        for (int dt = 0; dt < 4; dt++) {
            bf16x8 vf0 = *(const bf16x8*)((const char*)Vs[buf] + offK[0][dt]);
            bf16x8 vf1 = *(const bf16x8*)((const char*)Vs[buf] + offK[1][dt]);
            oacc[dt] = MFMA16(pf0, vf0, oacc[dt]);
            oacc[dt] = MFMA16(pf1, vf1, oacc[dt]);
        }
    }

#pragma unroll
    for (int off = 1; off < 16; off <<= 1)
#pragma unroll
        for (int r = 0; r < 4; r++)
            lpart[r] += __shfl_xor(lpart[r], off, 64);

    float rl[4];
#pragma unroll
    for (int r = 0; r < 4; r++) rl[r] = 1.0f / lpart[r];
#pragma unroll
    for (int dt = 0; dt < 4; dt++)
#pragma unroll
        for (int r = 0; r < 4; r++) {
            const int row = q0 + w * 16 + quad * 4 + r;
            outp[(size_t)(b * T + row) * 1024 + h * 64 + dt * 16 + l16] =
                __float2bfloat16(oacc[dt][r] * rl[r]);
        }
}

// --------------------------------- launcher --------------------------------
extern "C" void kernel_launch(void* const* d_in, const int* in_sizes, int n_in,
                              void* d_out, int out_size, void* d_ws, size_t ws_size,
                              hipStream_t stream) {
    const float* x     = (const float*)d_in[0];
    const float* Wqkv  = (const float*)d_in[1];
    const float* Wo    = (const float*)d_in[2];
    const float* b_o   = (const float*)d_in[3];
    const float* g1    = (const float*)d_in[4];
    const float* beta1 = (const float*)d_in[5];
    const float* g2    = (const float*)d_in[6];
    const float* beta2 = (const float*)d_in[7];
    const float* Wff1  = (const float*)d_in[8];
    const float* bff1  = (const float*)d_in[9];
    const float* Wff2  = (const float*)d_in[10];
    const float* bff2  = (const float*)d_in[11];

    char* ws = (char*)d_ws;
    size_t off = 0;
    auto alloc = [&](size_t bytes) {
        void* p = ws + off;
        off += (bytes + 255) & ~(size_t)255;
        return p;
    };
    __hip_bfloat16* Wqkv_t = (__hip_bfloat16*)alloc(3072ULL * 1024 * 2);
    __hip_bfloat16* Wo_t   = (__hip_bfloat16*)alloc(1024ULL * 1024 * 2);
    __hip_bfloat16* Wff1_t = (__hip_bfloat16*)alloc(4096ULL * 1024 * 2);
    __hip_bfloat16* Wff2_t = (__hip_bfloat16*)alloc(1024ULL * 4096 * 2);
    __hip_bfloat16* h_bf   = (__hip_bfloat16*)alloc(4096ULL * 1024 * 2);
    __hip_bfloat16* qkv_bf = (__hip_bfloat16*)alloc(4096ULL * 3072 * 2);
    __hip_bfloat16* att_bf = (__hip_bfloat16*)alloc(4096ULL * 1024 * 2);
    float*          x2     = (float*)alloc(4096ULL * 1024 * 4);
    __hip_bfloat16* ff1_bf = qkv_bf;              // dead by FF time
    __hip_bfloat16* vt     = (__hip_bfloat16*)x2; // dead before Wo-gemm writes x2

    const dim3 tb(32, 8);
    tconv_k<<<dim3(3072 / 32, 1024 / 32), tb, 0, stream>>>(Wqkv, Wqkv_t, 1024, 3072);
    tconv_k<<<dim3(1024 / 32, 1024 / 32), tb, 0, stream>>>(Wo,   Wo_t,   1024, 1024);
    tconv_k<<<dim3(4096 / 32, 1024 / 32), tb, 0, stream>>>(Wff1, Wff1_t, 1024, 4096);
    tconv_k<<<dim3(1024 / 32, 4096 / 32), tb, 0, stream>>>(Wff2, Wff2_t, 4096, 1024);

    ln_k<<<4096, 256, 0, stream>>>(x, g1, beta1, h_bf);
    gemm_k<0, 0, 0, 1><<<dim3(3072 / 128, 4096 / 128), 256, 0, stream>>>(
        h_bf, Wqkv_t, nullptr, nullptr, qkv_bf, 4096, 3072, 1024);
    vtrans_k<<<dim3(32, 32), dim3(64, 4), 0, stream>>>(qkv_bf, vt);
    attn_k<<<dim3(32, 32), 256, 0, stream>>>(qkv_bf, vt, att_bf);
    gemm64_k<1, 0, 1, 0><<<dim3(1024 / 64, 4096 / 128), 256, 0, stream>>>(
        att_bf, Wo_t, b_o, x, x2, 4096, 1024, 1024);
    ln_k<<<4096, 256, 0, stream>>>(x2, g2, beta2, h_bf);
    gemm_k<1, 1, 0, 1><<<dim3(4096 / 128, 4096 / 128), 256, 0, stream>>>(
        h_bf, Wff1_t, bff1, nullptr, ff1_bf, 4096, 4096, 1024);
    gemm64_k<1, 0, 1, 0><<<dim3(1024 / 64, 4096 / 128), 256, 0, stream>>>(
        ff1_bf, Wff2_t, bff2, x2, (float*)d_out, 4096, 1024, 4096);
}

// Round 8
// 331.447 us; speedup vs baseline: 1.6431x; 1.0277x over previous
//
#include <hip/hip_runtime.h>
#include <hip/hip_bf16.h>
#include <stdint.h>

// ---------------------------------------------------------------------------
// TransformerDecoderBlock on MI355X (gfx950).  B=2, T=2048, C=1024, H=16, hd=64.
// R7: XCD-aware block swizzle in both GEMMs (contiguous per-XCD chunk,
//     row-major -> A-panel L2 reuse; FETCH was 2.5x ideal).  Merged tconv.
// ---------------------------------------------------------------------------

typedef __attribute__((ext_vector_type(8))) short bf16x8;   // 8 bf16 in 4 VGPRs
typedef __attribute__((ext_vector_type(4))) float f32x4;

#define MFMA16(a, b, c) __builtin_amdgcn_mfma_f32_16x16x32_bf16((a), (b), (c), 0, 0, 0)

__device__ __forceinline__ void gload16(const void* g, void* l) {
    __builtin_amdgcn_global_load_lds(
        (const __attribute__((address_space(1))) char*)g,
        (__attribute__((address_space(3))) char*)l, 16, 0, 0);
}

// XCD-aware remap: contiguous chunk of work per XCD (XCD = dispatch id % 8).
__device__ __forceinline__ int xcd_swizzle(int flat, int nblk) {
    if ((nblk & 7) == 0) {
        const int per = nblk >> 3;
        flat = (flat & 7) * per + (flat >> 3);
    }
    return flat;
}

// ---------------- merged transpose + fp32->bf16 for all 4 weights -----------
// in: fp32 [K,N] row-major -> out: bf16 [N,K] row-major.  One launch.
__global__ __launch_bounds__(256) void tconv_all(
    const float* __restrict__ w0, __hip_bfloat16* __restrict__ o0,   // 1024x3072
    const float* __restrict__ w1, __hip_bfloat16* __restrict__ o1,   // 1024x1024
    const float* __restrict__ w2, __hip_bfloat16* __restrict__ o2,   // 1024x4096
    const float* __restrict__ w3, __hip_bfloat16* __restrict__ o3) { // 4096x1024
    __shared__ float tile[32][33];
    const int f = blockIdx.x;
    const float* in; __hip_bfloat16* out; int K, N, nx, t;
    if (f < 3072)      { in = w0; out = o0; K = 1024; N = 3072; nx = 96;  t = f; }
    else if (f < 4096) { in = w1; out = o1; K = 1024; N = 1024; nx = 32;  t = f - 3072; }
    else if (f < 8192) { in = w2; out = o2; K = 1024; N = 4096; nx = 128; t = f - 4096; }
    else               { in = w3; out = o3; K = 4096; N = 1024; nx = 32;  t = f - 8192; }
    const int n0 = (t % nx) * 32, k0 = (t / nx) * 32;
    const int tx = threadIdx.x, ty = threadIdx.y;   // block (32, 8)
    for (int i = ty; i < 32; i += 8)
        tile[i][tx] = in[(size_t)(k0 + i) * N + n0 + tx];
    __syncthreads();
    for (int i = ty; i < 32; i += 8)
        out[(size_t)(n0 + i) * K + k0 + tx] = __float2bfloat16(tile[tx][i]);
}

// --------------------------------- layernorm -------------------------------
__global__ __launch_bounds__(256) void ln_k(const float* __restrict__ x,
                                            const float* __restrict__ g,
                                            const float* __restrict__ beta,
                                            __hip_bfloat16* __restrict__ out) {
    const int row = blockIdx.x;
    const int tid = threadIdx.x;
    float4 v = ((const float4*)(x + (size_t)row * 1024))[tid];
    float s  = v.x + v.y + v.z + v.w;
    float s2 = v.x * v.x + v.y * v.y + v.z * v.z + v.w * v.w;
    for (int off = 1; off < 64; off <<= 1) {
        s  += __shfl_xor(s,  off, 64);
        s2 += __shfl_xor(s2, off, 64);
    }
    __shared__ float ss[4], ss2[4];
    const int w = tid >> 6, lane = tid & 63;
    if (lane == 0) { ss[w] = s; ss2[w] = s2; }
    __syncthreads();
    s  = ss[0] + ss[1] + ss[2] + ss[3];
    s2 = ss2[0] + ss2[1] + ss2[2] + ss2[3];
    const float mu  = s * (1.0f / 1024.0f);
    const float var = s2 * (1.0f / 1024.0f) - mu * mu;
    const float rs  = rsqrtf(var + 1e-5f);
    float4 gv = ((const float4*)g)[tid];
    float4 bv = ((const float4*)beta)[tid];
    __hip_bfloat16* o = out + (size_t)row * 1024 + tid * 4;
    o[0] = __float2bfloat16((v.x - mu) * rs * gv.x + bv.x);
    o[1] = __float2bfloat16((v.y - mu) * rs * gv.y + bv.y);
    o[2] = __float2bfloat16((v.z - mu) * rs * gv.z + bv.z);
    o[3] = __float2bfloat16((v.w - mu) * rs * gv.w + bv.w);
}

// ------------------- GEMM, BM=128 BN=128 BK=64, dbuf 1-barrier ---------------
template <int BIAS, int RELU, int RESID, int OUTBF>
__global__ __launch_bounds__(256, 2) void gemm_k(const __hip_bfloat16* __restrict__ A,
                                                 const __hip_bfloat16* __restrict__ Bt,
                                                 const float* __restrict__ bias,
                                                 const float* __restrict__ resid,
                                                 void* __restrict__ out,
                                                 int M, int N, int K) {
    __align__(16) __shared__ __hip_bfloat16 As[2][128 * 64];
    __align__(16) __shared__ __hip_bfloat16 Bs[2][128 * 64];

    const int tid  = threadIdx.x;
    const int lane = tid & 63, w = tid >> 6;
    const int wm = w >> 1, wn = w & 1;
    const int nbx = gridDim.x;
    const int flat = xcd_swizzle(blockIdx.y * nbx + blockIdx.x, nbx * gridDim.y);
    const int m0 = (flat / nbx) * 128, n0 = (flat % nbx) * 128;
    const int l16 = lane & 15, quad = lane >> 4;

    const int srw = lane >> 3;                 // 0..7
    const int scn = ((lane & 7) - srw) & 7;    // source chunk (swizzled)

    const __hip_bfloat16* ga[4];
    const __hip_bfloat16* gb[4];
#pragma unroll
    for (int i = 0; i < 4; i++) {
        const int row = i * 32 + w * 8 + srw;
        ga[i] = A  + (size_t)(m0 + row) * K + scn * 8;
        gb[i] = Bt + (size_t)(n0 + row) * K + scn * 8;
    }

    int offA[2][4], offB[2][4];
#pragma unroll
    for (int s = 0; s < 2; s++)
#pragma unroll
        for (int t = 0; t < 4; t++) {
            const int rA = wm * 64 + t * 16 + l16;
            offA[s][t] = (rA * 8 + ((s * 4 + quad + (rA & 7)) & 7)) * 16;
            const int rB = wn * 64 + t * 16 + l16;
            offB[s][t] = (rB * 8 + ((s * 4 + quad + (rB & 7)) & 7)) * 16;
        }

    f32x4 acc[4][4] = {};

#pragma unroll
    for (int i = 0; i < 4; i++) {
        gload16(ga[i], As[0] + (i * 256 + w * 64) * 8);
        gload16(gb[i], Bs[0] + (i * 256 + w * 64) * 8);
        ga[i] += 64; gb[i] += 64;
    }

    const int niter = K >> 6;
    for (int it = 0; it < niter; it++) {
        const int buf = it & 1;
        __syncthreads();   // drains prefetch into buf (issued prev iter)
        if (it + 1 < niter) {
#pragma unroll
            for (int i = 0; i < 4; i++) {
                gload16(ga[i], As[buf ^ 1] + (i * 256 + w * 64) * 8);
                gload16(gb[i], Bs[buf ^ 1] + (i * 256 + w * 64) * 8);
                ga[i] += 64; gb[i] += 64;
            }
        }

#pragma unroll
        for (int s = 0; s < 2; s++) {
            bf16x8 af[4], bfr[4];
#pragma unroll
            for (int t = 0; t < 4; t++) {
                af[t]  = *(const bf16x8*)((const char*)As[buf] + offA[s][t]);
                bfr[t] = *(const bf16x8*)((const char*)Bs[buf] + offB[s][t]);
            }
#pragma unroll
            for (int mt = 0; mt < 4; mt++)
#pragma unroll
                for (int nt = 0; nt < 4; nt++)
                    acc[mt][nt] = MFMA16(af[mt], bfr[nt], acc[mt][nt]);
        }
    }

#pragma unroll
    for (int mt = 0; mt < 4; mt++)
#pragma unroll
        for (int nt = 0; nt < 4; nt++) {
            const int row = m0 + wm * 64 + mt * 16 + quad * 4;
            const int col = n0 + wn * 64 + nt * 16 + l16;
            const float bv = BIAS ? bias[col] : 0.0f;
#pragma unroll
            for (int r = 0; r < 4; r++) {
                float v = acc[mt][nt][r] + bv;
                if (RELU) v = v > 0.0f ? v : 0.0f;
                const size_t idx = (size_t)(row + r) * N + col;
                if (RESID) v += resid[idx];
                if (OUTBF) ((__hip_bfloat16*)out)[idx] = __float2bfloat16(v);
                else       ((float*)out)[idx] = v;
            }
        }
}

// ------------------- GEMM, BM=128 BN=64 BK=64, dbuf 1-barrier ----------------
template <int BIAS, int RELU, int RESID, int OUTBF>
__global__ __launch_bounds__(256, 3) void gemm64_k(const __hip_bfloat16* __restrict__ A,
                                                   const __hip_bfloat16* __restrict__ Bt,
                                                   const float* __restrict__ bias,
                                                   const float* __restrict__ resid,
                                                   void* __restrict__ out,
                                                   int M, int N, int K) {
    __align__(16) __shared__ __hip_bfloat16 As[2][128 * 64];
    __align__(16) __shared__ __hip_bfloat16 Bs[2][64 * 64];

    const int tid  = threadIdx.x;
    const int lane = tid & 63, w = tid >> 6;
    const int wm = w >> 1, wn = w & 1;
    const int nbx = gridDim.x;
    const int flat = xcd_swizzle(blockIdx.y * nbx + blockIdx.x, nbx * gridDim.y);
    const int m0 = (flat / nbx) * 128, n0 = (flat % nbx) * 64;
    const int l16 = lane & 15, quad = lane >> 4;

    const int srw = lane >> 3;
    const int scn = ((lane & 7) - srw) & 7;

    const __hip_bfloat16* ga[4];
    const __hip_bfloat16* gb[2];
#pragma unroll
    for (int i = 0; i < 4; i++)
        ga[i] = A + (size_t)(m0 + i * 32 + w * 8 + srw) * K + scn * 8;
#pragma unroll
    for (int i = 0; i < 2; i++)
        gb[i] = Bt + (size_t)(n0 + i * 32 + w * 8 + srw) * K + scn * 8;

    int offA[2][4], offB[2][2];
#pragma unroll
    for (int s = 0; s < 2; s++) {
#pragma unroll
        for (int t = 0; t < 4; t++) {
            const int rA = wm * 64 + t * 16 + l16;
            offA[s][t] = (rA * 8 + ((s * 4 + quad + (rA & 7)) & 7)) * 16;
        }
#pragma unroll
        for (int t = 0; t < 2; t++) {
            const int rB = wn * 32 + t * 16 + l16;
            offB[s][t] = (rB * 8 + ((s * 4 + quad + (rB & 7)) & 7)) * 16;
        }
    }

    f32x4 acc[4][2] = {};

#pragma unroll
    for (int i = 0; i < 4; i++) {
        gload16(ga[i], As[0] + (i * 256 + w * 64) * 8);
        ga[i] += 64;
    }
#pragma unroll
    for (int i = 0; i < 2; i++) {
        gload16(gb[i], Bs[0] + (i * 256 + w * 64) * 8);
        gb[i] += 64;
    }

    const int niter = K >> 6;
    for (int it = 0; it < niter; it++) {
        const int buf = it & 1;
        __syncthreads();   // drains prefetch into buf
        if (it + 1 < niter) {
#pragma unroll
            for (int i = 0; i < 4; i++) {
                gload16(ga[i], As[buf ^ 1] + (i * 256 + w * 64) * 8);
                ga[i] += 64;
            }
#pragma unroll
            for (int i = 0; i < 2; i++) {
                gload16(gb[i], Bs[buf ^ 1] + (i * 256 + w * 64) * 8);
                gb[i] += 64;
            }
        }

#pragma unroll
        for (int s = 0; s < 2; s++) {
            bf16x8 af[4], bfr[2];
#pragma unroll
            for (int t = 0; t < 4; t++)
                af[t] = *(const bf16x8*)((const char*)As[buf] + offA[s][t]);
#pragma unroll
            for (int t = 0; t < 2; t++)
                bfr[t] = *(const bf16x8*)((const char*)Bs[buf] + offB[s][t]);
#pragma unroll
            for (int mt = 0; mt < 4; mt++)
#pragma unroll
                for (int nt = 0; nt < 2; nt++)
                    acc[mt][nt] = MFMA16(af[mt], bfr[nt], acc[mt][nt]);
        }
    }

#pragma unroll
    for (int mt = 0; mt < 4; mt++)
#pragma unroll
        for (int nt = 0; nt < 2; nt++) {
            const int row = m0 + wm * 64 + mt * 16 + quad * 4;
            const int col = n0 + wn * 32 + nt * 16 + l16;
            const float bv = BIAS ? bias[col] : 0.0f;
#pragma unroll
            for (int r = 0; r < 4; r++) {
                float v = acc[mt][nt][r] + bv;
                if (RELU) v = v > 0.0f ? v : 0.0f;
                const size_t idx = (size_t)(row + r) * N + col;
                if (RESID) v += resid[idx];
                if (OUTBF) ((__hip_bfloat16*)out)[idx] = __float2bfloat16(v);
                else       ((float*)out)[idx] = v;
            }
        }
}

// ----------------------- V transpose: qkv -> Vt[bh][d][T] -------------------
__global__ __launch_bounds__(256) void vtrans_k(const __hip_bfloat16* __restrict__ qkv,
                                                __hip_bfloat16* __restrict__ vt) {
    const int T = 2048, C3 = 3072;
    const int bh = blockIdx.y, b = bh >> 4, h = bh & 15;
    const int t0 = blockIdx.x * 64;
    const int tx = threadIdx.x, ty = threadIdx.y;   // block (64, 4)
    __shared__ __hip_bfloat16 tile[64][65];
#pragma unroll
    for (int j = 0; j < 16; j++) {
        const int tl = ty * 16 + j;
        tile[tl][tx] = qkv[(size_t)(b * T + t0 + tl) * C3 + 2048 + h * 64 + tx];
    }
    __syncthreads();
#pragma unroll
    for (int j = 0; j < 16; j++) {
        const int d = ty * 16 + j;
        vt[((size_t)bh * 64 + d) * 2048 + t0 + tx] = tile[tx][d];
    }
}

// ------------------------------ flash attention -----------------------------
__global__ __launch_bounds__(256, 3) void attn_k(const __hip_bfloat16* __restrict__ qkv,
                                                 const __hip_bfloat16* __restrict__ vt,
                                                 __hip_bfloat16* __restrict__ outp) {
    const int T = 2048, C3 = 3072;
    const int bh = blockIdx.x, b = bh >> 4, h = bh & 15;
    const int qt = 31 - blockIdx.y;           // heavy q-tiles dispatched first
    const int q0 = qt * 64;
    const int tid = threadIdx.x, lane = tid & 63, w = tid >> 6;
    const int l16 = lane & 15, quad = lane >> 4;

    __align__(16) __shared__ __hip_bfloat16 Ks[2][64 * 64];   // swizzled [key][d]
    __align__(16) __shared__ __hip_bfloat16 Vs[2][64 * 64];   // swizzled [d][key]
    __align__(16) __shared__ __hip_bfloat16 Pw[4][16 * 72];   // per-wave P

    const float sc = 0.125f * 1.44269504f;
    bf16x8 qf0, qf1;
    {
        const __hip_bfloat16* qp =
            qkv + (size_t)(b * T + q0 + w * 16 + l16) * C3 + h * 64;
        bf16x8 a = *(const bf16x8*)(qp + quad * 8);
        bf16x8 c = *(const bf16x8*)(qp + 32 + quad * 8);
#pragma unroll
        for (int i = 0; i < 8; i++) {
            union { unsigned int u; float f; } ua, uc;
            ua.u = ((unsigned int)(unsigned short)a[i]) << 16;
            uc.u = ((unsigned int)(unsigned short)c[i]) << 16;
            qf0[i] = (short)(__bfloat16_as_ushort(__float2bfloat16(ua.f * sc)));
            qf1[i] = (short)(__bfloat16_as_ushort(__float2bfloat16(uc.f * sc)));
        }
    }

    const int srw = lane >> 3;
    const int scn = ((lane & 7) - srw) & 7;
    const __hip_bfloat16* kp[2];
    const __hip_bfloat16* vp[2];
#pragma unroll
    for (int i = 0; i < 2; i++) {
        const int row = i * 32 + w * 8 + srw;
        kp[i] = qkv + (size_t)(b * T + row) * C3 + 1024 + h * 64 + scn * 8;
        vp[i] = vt + ((size_t)bh * 64 + row) * 2048 + scn * 8;
    }

    int offK[2][4];
#pragma unroll
    for (int s = 0; s < 2; s++)
#pragma unroll
        for (int t = 0; t < 4; t++) {
            const int rr = t * 16 + l16;
            offK[s][t] = (rr * 8 + ((s * 4 + quad + (rr & 7)) & 7)) * 16;
        }

    f32x4 oacc[4] = {};
    float lpart[4] = {0.0f, 0.0f, 0.0f, 0.0f};

#pragma unroll
    for (int i = 0; i < 2; i++) {
        gload16(kp[i], Ks[0] + (i * 256 + w * 64) * 8);
        gload16(vp[i], Vs[0] + (i * 256 + w * 64) * 8);
    }

    for (int kt = 0; kt <= qt; kt++) {
        const int buf = kt & 1;
        __syncthreads();
        if (kt < qt) {
#pragma unroll
            for (int i = 0; i < 2; i++) {
                gload16(kp[i] + (size_t)(kt + 1) * 64 * C3,
                        Ks[buf ^ 1] + (i * 256 + w * 64) * 8);
                gload16(vp[i] + (kt + 1) * 64,
                        Vs[buf ^ 1] + (i * 256 + w * 64) * 8);
            }
        }

        f32x4 s4[4];
#pragma unroll
        for (int nt = 0; nt < 4; nt++) {
            bf16x8 kf0 = *(const bf16x8*)((const char*)Ks[buf] + offK[0][nt]);
            bf16x8 kf1 = *(const bf16x8*)((const char*)Ks[buf] + offK[1][nt]);
            f32x4 z = {};
            z = MFMA16(qf0, kf0, z);
            z = MFMA16(qf1, kf1, z);
            s4[nt] = z;
        }

        const bool diag = (kt == qt);
        const int myrow = w * 16 + quad * 4;
#pragma unroll
        for (int nt = 0; nt < 4; nt++) {
            const int col = nt * 16 + l16;
#pragma unroll
            for (int r = 0; r < 4; r++) {
                float p = exp2f(s4[nt][r]);
                if (diag && col > myrow + r) p = 0.0f;
                lpart[r] += p;
                Pw[w][(quad * 4 + r) * 72 + col] = __float2bfloat16(p);
            }
        }

        asm volatile("s_waitcnt lgkmcnt(0)" ::: "memory");

        bf16x8 pf0 = *(const bf16x8*)(&Pw[w][l16 * 72 + quad * 8]);
        bf16x8 pf1 = *(const bf16x8*)(&Pw[w][l16 * 72 + 32 + quad * 8]);
#pragma unroll
        for (int dt = 0; dt < 4; dt++) {
            bf16x8 vf0 = *(const bf16x8*)((const char*)Vs[buf] + offK[0][dt]);
            bf16x8 vf1 = *(const bf16x8*)((const char*)Vs[buf] + offK[1][dt]);
            oacc[dt] = MFMA16(pf0, vf0, oacc[dt]);
            oacc[dt] = MFMA16(pf1, vf1, oacc[dt]);
        }
    }

#pragma unroll
    for (int off = 1; off < 16; off <<= 1)
#pragma unroll
        for (int r = 0; r < 4; r++)
            lpart[r] += __shfl_xor(lpart[r], off, 64);

    float rl[4];
#pragma unroll
    for (int r = 0; r < 4; r++) rl[r] = 1.0f / lpart[r];
#pragma unroll
    for (int dt = 0; dt < 4; dt++)
#pragma unroll
        for (int r = 0; r < 4; r++) {
            const int row = q0 + w * 16 + quad * 4 + r;
            outp[(size_t)(b * T + row) * 1024 + h * 64 + dt * 16 + l16] =
                __float2bfloat16(oacc[dt][r] * rl[r]);
        }
}

// --------------------------------- launcher --------------------------------
extern "C" void kernel_launch(void* const* d_in, const int* in_sizes, int n_in,
                              void* d_out, int out_size, void* d_ws, size_t ws_size,
                              hipStream_t stream) {
    const float* x     = (const float*)d_in[0];
    const float* Wqkv  = (const float*)d_in[1];
    const float* Wo    = (const float*)d_in[2];
    const float* b_o   = (const float*)d_in[3];
    const float* g1    = (const float*)d_in[4];
    const float* beta1 = (const float*)d_in[5];
    const float* g2    = (const float*)d_in[6];
    const float* beta2 = (const float*)d_in[7];
    const float* Wff1  = (const float*)d_in[8];
    const float* bff1  = (const float*)d_in[9];
    const float* Wff2  = (const float*)d_in[10];
    const float* bff2  = (const float*)d_in[11];

    char* ws = (char*)d_ws;
    size_t off = 0;
    auto alloc = [&](size_t bytes) {
        void* p = ws + off;
        off += (bytes + 255) & ~(size_t)255;
        return p;
    };
    __hip_bfloat16* Wqkv_t = (__hip_bfloat16*)alloc(3072ULL * 1024 * 2);
    __hip_bfloat16* Wo_t   = (__hip_bfloat16*)alloc(1024ULL * 1024 * 2);
    __hip_bfloat16* Wff1_t = (__hip_bfloat16*)alloc(4096ULL * 1024 * 2);
    __hip_bfloat16* Wff2_t = (__hip_bfloat16*)alloc(1024ULL * 4096 * 2);
    __hip_bfloat16* h_bf   = (__hip_bfloat16*)alloc(4096ULL * 1024 * 2);
    __hip_bfloat16* qkv_bf = (__hip_bfloat16*)alloc(4096ULL * 3072 * 2);
    __hip_bfloat16* att_bf = (__hip_bfloat16*)alloc(4096ULL * 1024 * 2);
    float*          x2     = (float*)alloc(4096ULL * 1024 * 4);
    __hip_bfloat16* ff1_bf = qkv_bf;              // dead by FF time
    __hip_bfloat16* vt     = (__hip_bfloat16*)x2; // dead before Wo-gemm writes x2

    tconv_all<<<12288, dim3(32, 8), 0, stream>>>(Wqkv, Wqkv_t, Wo, Wo_t,
                                                 Wff1, Wff1_t, Wff2, Wff2_t);

    ln_k<<<4096, 256, 0, stream>>>(x, g1, beta1, h_bf);
    gemm_k<0, 0, 0, 1><<<dim3(3072 / 128, 4096 / 128), 256, 0, stream>>>(
        h_bf, Wqkv_t, nullptr, nullptr, qkv_bf, 4096, 3072, 1024);
    vtrans_k<<<dim3(32, 32), dim3(64, 4), 0, stream>>>(qkv_bf, vt);
    attn_k<<<dim3(32, 32), 256, 0, stream>>>(qkv_bf, vt, att_bf);
    gemm64_k<1, 0, 1, 0><<<dim3(1024 / 64, 4096 / 128), 256, 0, stream>>>(
        att_bf, Wo_t, b_o, x, x2, 4096, 1024, 1024);
    ln_k<<<4096, 256, 0, stream>>>(x2, g2, beta2, h_bf);
    gemm_k<1, 1, 0, 1><<<dim3(4096 / 128, 4096 / 128), 256, 0, stream>>>(
        h_bf, Wff1_t, bff1, nullptr, ff1_bf, 4096, 4096, 1024);
    gemm64_k<1, 0, 1, 0><<<dim3(1024 / 64, 4096 / 128), 256, 0, stream>>>(
        ff1_bf, Wff2_t, bff2, x2, (float*)d_out, 4096, 1024, 4096);
}

// Round 9
// 327.625 us; speedup vs baseline: 1.6622x; 1.0117x over previous
//
#include <hip/hip_runtime.h>
#include <hip/hip_bf16.h>
#include <stdint.h>

// ---------------------------------------------------------------------------
// TransformerDecoderBlock on MI355X (gfx950).  B=2, T=2048, C=1024, H=16, hd=64.
// R8: N=1024 GEMMs (Wo, FF2) -> 64x64 tiles, 4 blocks/CU (grid-limited
//     occupancy was the latency wall: FETCH ideal but dur unchanged in R7).
// ---------------------------------------------------------------------------

typedef __attribute__((ext_vector_type(8))) short bf16x8;   // 8 bf16 in 4 VGPRs
typedef __attribute__((ext_vector_type(4))) float f32x4;

#define MFMA16(a, b, c) __builtin_amdgcn_mfma_f32_16x16x32_bf16((a), (b), (c), 0, 0, 0)

__device__ __forceinline__ void gload16(const void* g, void* l) {
    __builtin_amdgcn_global_load_lds(
        (const __attribute__((address_space(1))) char*)g,
        (__attribute__((address_space(3))) char*)l, 16, 0, 0);
}

// XCD-aware remap: contiguous chunk of work per XCD (XCD = dispatch id % 8).
__device__ __forceinline__ int xcd_swizzle(int flat, int nblk) {
    if ((nblk & 7) == 0) {
        const int per = nblk >> 3;
        flat = (flat & 7) * per + (flat >> 3);
    }
    return flat;
}

// ---------------- merged transpose + fp32->bf16 for all 4 weights -----------
__global__ __launch_bounds__(256) void tconv_all(
    const float* __restrict__ w0, __hip_bfloat16* __restrict__ o0,   // 1024x3072
    const float* __restrict__ w1, __hip_bfloat16* __restrict__ o1,   // 1024x1024
    const float* __restrict__ w2, __hip_bfloat16* __restrict__ o2,   // 1024x4096
    const float* __restrict__ w3, __hip_bfloat16* __restrict__ o3) { // 4096x1024
    __shared__ float tile[32][33];
    const int f = blockIdx.x;
    const float* in; __hip_bfloat16* out; int K, N, nx, t;
    if (f < 3072)      { in = w0; out = o0; K = 1024; N = 3072; nx = 96;  t = f; }
    else if (f < 4096) { in = w1; out = o1; K = 1024; N = 1024; nx = 32;  t = f - 3072; }
    else if (f < 8192) { in = w2; out = o2; K = 1024; N = 4096; nx = 128; t = f - 4096; }
    else               { in = w3; out = o3; K = 4096; N = 1024; nx = 32;  t = f - 8192; }
    const int n0 = (t % nx) * 32, k0 = (t / nx) * 32;
    const int tx = threadIdx.x, ty = threadIdx.y;   // block (32, 8)
    for (int i = ty; i < 32; i += 8)
        tile[i][tx] = in[(size_t)(k0 + i) * N + n0 + tx];
    __syncthreads();
    for (int i = ty; i < 32; i += 8)
        out[(size_t)(n0 + i) * K + k0 + tx] = __float2bfloat16(tile[tx][i]);
}

// --------------------------------- layernorm -------------------------------
__global__ __launch_bounds__(256) void ln_k(const float* __restrict__ x,
                                            const float* __restrict__ g,
                                            const float* __restrict__ beta,
                                            __hip_bfloat16* __restrict__ out) {
    const int row = blockIdx.x;
    const int tid = threadIdx.x;
    float4 v = ((const float4*)(x + (size_t)row * 1024))[tid];
    float s  = v.x + v.y + v.z + v.w;
    float s2 = v.x * v.x + v.y * v.y + v.z * v.z + v.w * v.w;
    for (int off = 1; off < 64; off <<= 1) {
        s  += __shfl_xor(s,  off, 64);
        s2 += __shfl_xor(s2, off, 64);
    }
    __shared__ float ss[4], ss2[4];
    const int w = tid >> 6, lane = tid & 63;
    if (lane == 0) { ss[w] = s; ss2[w] = s2; }
    __syncthreads();
    s  = ss[0] + ss[1] + ss[2] + ss[3];
    s2 = ss2[0] + ss2[1] + ss2[2] + ss2[3];
    const float mu  = s * (1.0f / 1024.0f);
    const float var = s2 * (1.0f / 1024.0f) - mu * mu;
    const float rs  = rsqrtf(var + 1e-5f);
    float4 gv = ((const float4*)g)[tid];
    float4 bv = ((const float4*)beta)[tid];
    __hip_bfloat16* o = out + (size_t)row * 1024 + tid * 4;
    o[0] = __float2bfloat16((v.x - mu) * rs * gv.x + bv.x);
    o[1] = __float2bfloat16((v.y - mu) * rs * gv.y + bv.y);
    o[2] = __float2bfloat16((v.z - mu) * rs * gv.z + bv.z);
    o[3] = __float2bfloat16((v.w - mu) * rs * gv.w + bv.w);
}

// ------------------- GEMM, BM=128 BN=128 BK=64, dbuf 1-barrier ---------------
template <int BIAS, int RELU, int RESID, int OUTBF>
__global__ __launch_bounds__(256, 2) void gemm_k(const __hip_bfloat16* __restrict__ A,
                                                 const __hip_bfloat16* __restrict__ Bt,
                                                 const float* __restrict__ bias,
                                                 const float* __restrict__ resid,
                                                 void* __restrict__ out,
                                                 int M, int N, int K) {
    __align__(16) __shared__ __hip_bfloat16 As[2][128 * 64];
    __align__(16) __shared__ __hip_bfloat16 Bs[2][128 * 64];

    const int tid  = threadIdx.x;
    const int lane = tid & 63, w = tid >> 6;
    const int wm = w >> 1, wn = w & 1;
    const int nbx = gridDim.x;
    const int flat = xcd_swizzle(blockIdx.y * nbx + blockIdx.x, nbx * gridDim.y);
    const int m0 = (flat / nbx) * 128, n0 = (flat % nbx) * 128;
    const int l16 = lane & 15, quad = lane >> 4;

    const int srw = lane >> 3;                 // 0..7
    const int scn = ((lane & 7) - srw) & 7;    // source chunk (swizzled)

    const __hip_bfloat16* ga[4];
    const __hip_bfloat16* gb[4];
#pragma unroll
    for (int i = 0; i < 4; i++) {
        const int row = i * 32 + w * 8 + srw;
        ga[i] = A  + (size_t)(m0 + row) * K + scn * 8;
        gb[i] = Bt + (size_t)(n0 + row) * K + scn * 8;
    }

    int offA[2][4], offB[2][4];
#pragma unroll
    for (int s = 0; s < 2; s++)
#pragma unroll
        for (int t = 0; t < 4; t++) {
            const int rA = wm * 64 + t * 16 + l16;
            offA[s][t] = (rA * 8 + ((s * 4 + quad + (rA & 7)) & 7)) * 16;
            const int rB = wn * 64 + t * 16 + l16;
            offB[s][t] = (rB * 8 + ((s * 4 + quad + (rB & 7)) & 7)) * 16;
        }

    f32x4 acc[4][4] = {};

#pragma unroll
    for (int i = 0; i < 4; i++) {
        gload16(ga[i], As[0] + (i * 256 + w * 64) * 8);
        gload16(gb[i], Bs[0] + (i * 256 + w * 64) * 8);
        ga[i] += 64; gb[i] += 64;
    }

    const int niter = K >> 6;
    for (int it = 0; it < niter; it++) {
        const int buf = it & 1;
        __syncthreads();   // drains prefetch into buf (issued prev iter)
        if (it + 1 < niter) {
#pragma unroll
            for (int i = 0; i < 4; i++) {
                gload16(ga[i], As[buf ^ 1] + (i * 256 + w * 64) * 8);
                gload16(gb[i], Bs[buf ^ 1] + (i * 256 + w * 64) * 8);
                ga[i] += 64; gb[i] += 64;
            }
        }

#pragma unroll
        for (int s = 0; s < 2; s++) {
            bf16x8 af[4], bfr[4];
#pragma unroll
            for (int t = 0; t < 4; t++) {
                af[t]  = *(const bf16x8*)((const char*)As[buf] + offA[s][t]);
                bfr[t] = *(const bf16x8*)((const char*)Bs[buf] + offB[s][t]);
            }
#pragma unroll
            for (int mt = 0; mt < 4; mt++)
#pragma unroll
                for (int nt = 0; nt < 4; nt++)
                    acc[mt][nt] = MFMA16(af[mt], bfr[nt], acc[mt][nt]);
        }
    }

#pragma unroll
    for (int mt = 0; mt < 4; mt++)
#pragma unroll
        for (int nt = 0; nt < 4; nt++) {
            const int row = m0 + wm * 64 + mt * 16 + quad * 4;
            const int col = n0 + wn * 64 + nt * 16 + l16;
            const float bv = BIAS ? bias[col] : 0.0f;
#pragma unroll
            for (int r = 0; r < 4; r++) {
                float v = acc[mt][nt][r] + bv;
                if (RELU) v = v > 0.0f ? v : 0.0f;
                const size_t idx = (size_t)(row + r) * N + col;
                if (RESID) v += resid[idx];
                if (OUTBF) ((__hip_bfloat16*)out)[idx] = __float2bfloat16(v);
                else       ((float*)out)[idx] = v;
            }
        }
}

// ------------------- GEMM, BM=64 BN=64 BK=64, dbuf 1-barrier -----------------
// For N=1024 outputs: grid (N/64)x(M/64) = 1024 blocks -> 4 blocks/CU.
template <int BIAS, int RELU, int RESID, int OUTBF>
__global__ __launch_bounds__(256, 4) void gemm6464_k(const __hip_bfloat16* __restrict__ A,
                                                     const __hip_bfloat16* __restrict__ Bt,
                                                     const float* __restrict__ bias,
                                                     const float* __restrict__ resid,
                                                     void* __restrict__ out,
                                                     int M, int N, int K) {
    __align__(16) __shared__ __hip_bfloat16 As[2][64 * 64];
    __align__(16) __shared__ __hip_bfloat16 Bs[2][64 * 64];

    const int tid  = threadIdx.x;
    const int lane = tid & 63, w = tid >> 6;
    const int wm = w >> 1, wn = w & 1;             // 2x2 wave grid of 32x32
    const int nbx = gridDim.x;
    const int flat = xcd_swizzle(blockIdx.y * nbx + blockIdx.x, nbx * gridDim.y);
    const int m0 = (flat / nbx) * 64, n0 = (flat % nbx) * 64;
    const int l16 = lane & 15, quad = lane >> 4;

    const int srw = lane >> 3;
    const int scn = ((lane & 7) - srw) & 7;

    const __hip_bfloat16* ga[2];
    const __hip_bfloat16* gb[2];
#pragma unroll
    for (int i = 0; i < 2; i++) {
        const int row = i * 32 + w * 8 + srw;
        ga[i] = A  + (size_t)(m0 + row) * K + scn * 8;
        gb[i] = Bt + (size_t)(n0 + row) * K + scn * 8;
    }

    int offA[2][2], offB[2][2];
#pragma unroll
    for (int s = 0; s < 2; s++)
#pragma unroll
        for (int t = 0; t < 2; t++) {
            const int rA = wm * 32 + t * 16 + l16;
            offA[s][t] = (rA * 8 + ((s * 4 + quad + (rA & 7)) & 7)) * 16;
            const int rB = wn * 32 + t * 16 + l16;
            offB[s][t] = (rB * 8 + ((s * 4 + quad + (rB & 7)) & 7)) * 16;
        }

    f32x4 acc[2][2] = {};

#pragma unroll
    for (int i = 0; i < 2; i++) {
        gload16(ga[i], As[0] + (i * 256 + w * 64) * 8);
        gload16(gb[i], Bs[0] + (i * 256 + w * 64) * 8);
        ga[i] += 64; gb[i] += 64;
    }

    const int niter = K >> 6;
    for (int it = 0; it < niter; it++) {
        const int buf = it & 1;
        __syncthreads();   // drains prefetch into buf
        if (it + 1 < niter) {
#pragma unroll
            for (int i = 0; i < 2; i++) {
                gload16(ga[i], As[buf ^ 1] + (i * 256 + w * 64) * 8);
                gload16(gb[i], Bs[buf ^ 1] + (i * 256 + w * 64) * 8);
                ga[i] += 64; gb[i] += 64;
            }
        }

#pragma unroll
        for (int s = 0; s < 2; s++) {
            bf16x8 af[2], bfr[2];
#pragma unroll
            for (int t = 0; t < 2; t++) {
                af[t]  = *(const bf16x8*)((const char*)As[buf] + offA[s][t]);
                bfr[t] = *(const bf16x8*)((const char*)Bs[buf] + offB[s][t]);
            }
#pragma unroll
            for (int mt = 0; mt < 2; mt++)
#pragma unroll
                for (int nt = 0; nt < 2; nt++)
                    acc[mt][nt] = MFMA16(af[mt], bfr[nt], acc[mt][nt]);
        }
    }

#pragma unroll
    for (int mt = 0; mt < 2; mt++)
#pragma unroll
        for (int nt = 0; nt < 2; nt++) {
            const int row = m0 + wm * 32 + mt * 16 + quad * 4;
            const int col = n0 + wn * 32 + nt * 16 + l16;
            const float bv = BIAS ? bias[col] : 0.0f;
#pragma unroll
            for (int r = 0; r < 4; r++) {
                float v = acc[mt][nt][r] + bv;
                if (RELU) v = v > 0.0f ? v : 0.0f;
                const size_t idx = (size_t)(row + r) * N + col;
                if (RESID) v += resid[idx];
                if (OUTBF) ((__hip_bfloat16*)out)[idx] = __float2bfloat16(v);
                else       ((float*)out)[idx] = v;
            }
        }
}

// ----------------------- V transpose: qkv -> Vt[bh][d][T] -------------------
__global__ __launch_bounds__(256) void vtrans_k(const __hip_bfloat16* __restrict__ qkv,
                                                __hip_bfloat16* __restrict__ vt) {
    const int T = 2048, C3 = 3072;
    const int bh = blockIdx.y, b = bh >> 4, h = bh & 15;
    const int t0 = blockIdx.x * 64;
    const int tx = threadIdx.x, ty = threadIdx.y;   // block (64, 4)
    __shared__ __hip_bfloat16 tile[64][65];
#pragma unroll
    for (int j = 0; j < 16; j++) {
        const int tl = ty * 16 + j;
        tile[tl][tx] = qkv[(size_t)(b * T + t0 + tl) * C3 + 2048 + h * 64 + tx];
    }
    __syncthreads();
#pragma unroll
    for (int j = 0; j < 16; j++) {
        const int d = ty * 16 + j;
        vt[((size_t)bh * 64 + d) * 2048 + t0 + tx] = tile[tx][d];
    }
}

// ------------------------------ flash attention -----------------------------
__global__ __launch_bounds__(256, 3) void attn_k(const __hip_bfloat16* __restrict__ qkv,
                                                 const __hip_bfloat16* __restrict__ vt,
                                                 __hip_bfloat16* __restrict__ outp) {
    const int T = 2048, C3 = 3072;
    const int bh = blockIdx.x, b = bh >> 4, h = bh & 15;
    const int qt = 31 - blockIdx.y;           // heavy q-tiles dispatched first
    const int q0 = qt * 64;
    const int tid = threadIdx.x, lane = tid & 63, w = tid >> 6;
    const int l16 = lane & 15, quad = lane >> 4;

    __align__(16) __shared__ __hip_bfloat16 Ks[2][64 * 64];   // swizzled [key][d]
    __align__(16) __shared__ __hip_bfloat16 Vs[2][64 * 64];   // swizzled [d][key]
    __align__(16) __shared__ __hip_bfloat16 Pw[4][16 * 72];   // per-wave P

    const float sc = 0.125f * 1.44269504f;
    bf16x8 qf0, qf1;
    {
        const __hip_bfloat16* qp =
            qkv + (size_t)(b * T + q0 + w * 16 + l16) * C3 + h * 64;
        bf16x8 a = *(const bf16x8*)(qp + quad * 8);
        bf16x8 c = *(const bf16x8*)(qp + 32 + quad * 8);
#pragma unroll
        for (int i = 0; i < 8; i++) {
            union { unsigned int u; float f; } ua, uc;
            ua.u = ((unsigned int)(unsigned short)a[i]) << 16;
            uc.u = ((unsigned int)(unsigned short)c[i]) << 16;
            qf0[i] = (short)(__bfloat16_as_ushort(__float2bfloat16(ua.f * sc)));
            qf1[i] = (short)(__bfloat16_as_ushort(__float2bfloat16(uc.f * sc)));
        }
    }

    const int srw = lane >> 3;
    const int scn = ((lane & 7) - srw) & 7;
    const __hip_bfloat16* kp[2];
    const __hip_bfloat16* vp[2];
#pragma unroll
    for (int i = 0; i < 2; i++) {
        const int row = i * 32 + w * 8 + srw;
        kp[i] = qkv + (size_t)(b * T + row) * C3 + 1024 + h * 64 + scn * 8;
        vp[i] = vt + ((size_t)bh * 64 + row) * 2048 + scn * 8;
    }

    int offK[2][4];
#pragma unroll
    for (int s = 0; s < 2; s++)
#pragma unroll
        for (int t = 0; t < 4; t++) {
            const int rr = t * 16 + l16;
            offK[s][t] = (rr * 8 + ((s * 4 + quad + (rr & 7)) & 7)) * 16;
        }

    f32x4 oacc[4] = {};
    float lpart[4] = {0.0f, 0.0f, 0.0f, 0.0f};

#pragma unroll
    for (int i = 0; i < 2; i++) {
        gload16(kp[i], Ks[0] + (i * 256 + w * 64) * 8);
        gload16(vp[i], Vs[0] + (i * 256 + w * 64) * 8);
    }

    for (int kt = 0; kt <= qt; kt++) {
        const int buf = kt & 1;
        __syncthreads();
        if (kt < qt) {
#pragma unroll
            for (int i = 0; i < 2; i++) {
                gload16(kp[i] + (size_t)(kt + 1) * 64 * C3,
                        Ks[buf ^ 1] + (i * 256 + w * 64) * 8);
                gload16(vp[i] + (kt + 1) * 64,
                        Vs[buf ^ 1] + (i * 256 + w * 64) * 8);
            }
        }

        f32x4 s4[4];
#pragma unroll
        for (int nt = 0; nt < 4; nt++) {
            bf16x8 kf0 = *(const bf16x8*)((const char*)Ks[buf] + offK[0][nt]);
            bf16x8 kf1 = *(const bf16x8*)((const char*)Ks[buf] + offK[1][nt]);
            f32x4 z = {};
            z = MFMA16(qf0, kf0, z);
            z = MFMA16(qf1, kf1, z);
            s4[nt] = z;
        }

        const bool diag = (kt == qt);
        const int myrow = w * 16 + quad * 4;
#pragma unroll
        for (int nt = 0; nt < 4; nt++) {
            const int col = nt * 16 + l16;
#pragma unroll
            for (int r = 0; r < 4; r++) {
                float p = exp2f(s4[nt][r]);
                if (diag && col > myrow + r) p = 0.0f;
                lpart[r] += p;
                Pw[w][(quad * 4 + r) * 72 + col] = __float2bfloat16(p);
            }
        }

        asm volatile("s_waitcnt lgkmcnt(0)" ::: "memory");

        bf16x8 pf0 = *(const bf16x8*)(&Pw[w][l16 * 72 + quad * 8]);
        bf16x8 pf1 = *(const bf16x8*)(&Pw[w][l16 * 72 + 32 + quad * 8]);
#pragma unroll
        for (int dt = 0; dt < 4; dt++) {
            bf16x8 vf0 = *(const bf16x8*)((const char*)Vs[buf] + offK[0][dt]);
            bf16x8 vf1 = *(const bf16x8*)((const char*)Vs[buf] + offK[1][dt]);
            oacc[dt] = MFMA16(pf0, vf0, oacc[dt]);
            oacc[dt] = MFMA16(pf1, vf1, oacc[dt]);
        }
    }

#pragma unroll
    for (int off = 1; off < 16; off <<= 1)
#pragma unroll
        for (int r = 0; r < 4; r++)
            lpart[r] += __shfl_xor(lpart[r], off, 64);

    float rl[4];
#pragma unroll
    for (int r = 0; r < 4; r++) rl[r] = 1.0f / lpart[r];
#pragma unroll
    for (int dt = 0; dt < 4; dt++)
#pragma unroll
        for (int r = 0; r < 4; r++) {
            const int row = q0 + w * 16 + quad * 4 + r;
            outp[(size_t)(b * T + row) * 1024 + h * 64 + dt * 16 + l16] =
                __float2bfloat16(oacc[dt][r] * rl[r]);
        }
}

// --------------------------------- launcher --------------------------------
extern "C" void kernel_launch(void* const* d_in, const int* in_sizes, int n_in,
                              void* d_out, int out_size, void* d_ws, size_t ws_size,
                              hipStream_t stream) {
    const float* x     = (const float*)d_in[0];
    const float* Wqkv  = (const float*)d_in[1];
    const float* Wo    = (const float*)d_in[2];
    const float* b_o   = (const float*)d_in[3];
    const float* g1    = (const float*)d_in[4];
    const float* beta1 = (const float*)d_in[5];
    const float* g2    = (const float*)d_in[6];
    const float* beta2 = (const float*)d_in[7];
    const float* Wff1  = (const float*)d_in[8];
    const float* bff1  = (const float*)d_in[9];
    const float* Wff2  = (const float*)d_in[10];
    const float* bff2  = (const float*)d_in[11];

    char* ws = (char*)d_ws;
    size_t off = 0;
    auto alloc = [&](size_t bytes) {
        void* p = ws + off;
        off += (bytes + 255) & ~(size_t)255;
        return p;
    };
    __hip_bfloat16* Wqkv_t = (__hip_bfloat16*)alloc(3072ULL * 1024 * 2);
    __hip_bfloat16* Wo_t   = (__hip_bfloat16*)alloc(1024ULL * 1024 * 2);
    __hip_bfloat16* Wff1_t = (__hip_bfloat16*)alloc(4096ULL * 1024 * 2);
    __hip_bfloat16* Wff2_t = (__hip_bfloat16*)alloc(1024ULL * 4096 * 2);
    __hip_bfloat16* h_bf   = (__hip_bfloat16*)alloc(4096ULL * 1024 * 2);
    __hip_bfloat16* qkv_bf = (__hip_bfloat16*)alloc(4096ULL * 3072 * 2);
    __hip_bfloat16* att_bf = (__hip_bfloat16*)alloc(4096ULL * 1024 * 2);
    float*          x2     = (float*)alloc(4096ULL * 1024 * 4);
    __hip_bfloat16* ff1_bf = qkv_bf;              // dead by FF time
    __hip_bfloat16* vt     = (__hip_bfloat16*)x2; // dead before Wo-gemm writes x2

    tconv_all<<<12288, dim3(32, 8), 0, stream>>>(Wqkv, Wqkv_t, Wo, Wo_t,
                                                 Wff1, Wff1_t, Wff2, Wff2_t);

    ln_k<<<4096, 256, 0, stream>>>(x, g1, beta1, h_bf);
    gemm_k<0, 0, 0, 1><<<dim3(3072 / 128, 4096 / 128), 256, 0, stream>>>(
        h_bf, Wqkv_t, nullptr, nullptr, qkv_bf, 4096, 3072, 1024);
    vtrans_k<<<dim3(32, 32), dim3(64, 4), 0, stream>>>(qkv_bf, vt);
    attn_k<<<dim3(32, 32), 256, 0, stream>>>(qkv_bf, vt, att_bf);
    gemm6464_k<1, 0, 1, 0><<<dim3(1024 / 64, 4096 / 64), 256, 0, stream>>>(
        att_bf, Wo_t, b_o, x, x2, 4096, 1024, 1024);
    ln_k<<<4096, 256, 0, stream>>>(x2, g2, beta2, h_bf);
    gemm_k<1, 1, 0, 1><<<dim3(4096 / 128, 4096 / 128), 256, 0, stream>>>(
        h_bf, Wff1_t, bff1, nullptr, ff1_bf, 4096, 4096, 1024);
    gemm6464_k<1, 0, 1, 0><<<dim3(1024 / 64, 4096 / 64), 256, 0, stream>>>(
        ff1_bf, Wff2_t, bff2, x2, (float*)d_out, 4096, 1024, 4096);
}